// Round 5
// baseline (585.721 us; speedup 1.0000x reference)
//
#include <hip/hip_runtime.h>
#include <hip/hip_bf16.h>
#include <math.h>

#define NEG_INF -3.0e38f

typedef __attribute__((ext_vector_type(8))) short bf16x8;
typedef __attribute__((ext_vector_type(4))) float f32x4;

__device__ inline short f2bf(float f) {
    __hip_bfloat16 h = __float2bfloat16(f);
    return *reinterpret_cast<short*>(&h);
}

// ---------------------------------------------------------------------------
// bf16 MFMA GEMM: C[m][n] = scale * sum_k A[m][k]*B[n][k] (+bias[n])
// 128x128 tile, 4 waves, BK=32, mfma_f32_16x16x32_bf16.
// ---------------------------------------------------------------------------
__global__ __launch_bounds__(256) void gemm_mfma(
    const float* __restrict__ A, long lda, long sAb, long sAh,
    const float* __restrict__ B, long ldb, long sBb, long sBh,
    float* __restrict__ C, long ldc, long sCb, long sCh,
    int K, const float* __restrict__ bias, float scale, int hDiv)
{
    int bz = blockIdx.z;
    int bb = bz / hDiv, hh = bz % hDiv;
    A += bb * sAb + hh * sAh;
    B += bb * sBb + hh * sBh;
    C += bb * sCb + hh * sCh;
    int bm = blockIdx.y * 128, bn = blockIdx.x * 128;

    __shared__ __align__(16) short Asub[4096];
    __shared__ __align__(16) short Bsub[4096];

    int tid = threadIdx.x;
    int lane = tid & 63;
    int wave = tid >> 6;
    int wr = wave >> 1, wc = wave & 1;
    int l15 = lane & 15, l4 = lane >> 4;

    f32x4 acc[4][4] = {};

    int sr = tid >> 1;
    int sh = tid & 1;
    const float* gA = A + (long)(bm + sr) * lda + sh * 16;
    const float* gB = B + (long)(bn + sr) * ldb + sh * 16;
    short* wA = Asub + (sr >> 4) * 512 + (sr & 15) * 8 + sh * 256;
    short* wB = Bsub + (sr >> 4) * 512 + (sr & 15) * 8 + sh * 256;

    for (int k0 = 0; k0 < K; k0 += 32) {
        float4 a0 = *(const float4*)(gA + k0);
        float4 a1 = *(const float4*)(gA + k0 + 4);
        float4 a2 = *(const float4*)(gA + k0 + 8);
        float4 a3 = *(const float4*)(gA + k0 + 12);
        float4 b0 = *(const float4*)(gB + k0);
        float4 b1 = *(const float4*)(gB + k0 + 4);
        float4 b2 = *(const float4*)(gB + k0 + 8);
        float4 b3 = *(const float4*)(gB + k0 + 12);
        bf16x8 ua0, ua1, ub0, ub1;
        ua0[0]=f2bf(a0.x); ua0[1]=f2bf(a0.y); ua0[2]=f2bf(a0.z); ua0[3]=f2bf(a0.w);
        ua0[4]=f2bf(a1.x); ua0[5]=f2bf(a1.y); ua0[6]=f2bf(a1.z); ua0[7]=f2bf(a1.w);
        ua1[0]=f2bf(a2.x); ua1[1]=f2bf(a2.y); ua1[2]=f2bf(a2.z); ua1[3]=f2bf(a2.w);
        ua1[4]=f2bf(a3.x); ua1[5]=f2bf(a3.y); ua1[6]=f2bf(a3.z); ua1[7]=f2bf(a3.w);
        ub0[0]=f2bf(b0.x); ub0[1]=f2bf(b0.y); ub0[2]=f2bf(b0.z); ub0[3]=f2bf(b0.w);
        ub0[4]=f2bf(b1.x); ub0[5]=f2bf(b1.y); ub0[6]=f2bf(b1.z); ub0[7]=f2bf(b1.w);
        ub1[0]=f2bf(b2.x); ub1[1]=f2bf(b2.y); ub1[2]=f2bf(b2.z); ub1[3]=f2bf(b2.w);
        ub1[4]=f2bf(b3.x); ub1[5]=f2bf(b3.y); ub1[6]=f2bf(b3.z); ub1[7]=f2bf(b3.w);
        *(bf16x8*)wA = ua0;
        *(bf16x8*)(wA + 128) = ua1;
        *(bf16x8*)wB = ub0;
        *(bf16x8*)(wB + 128) = ub1;
        __syncthreads();

        bf16x8 af[4], bfr[4];
#pragma unroll
        for (int mi = 0; mi < 4; mi++)
            af[mi] = *(const bf16x8*)(Asub + (wr * 4 + mi) * 512 + l4 * 128 + l15 * 8);
#pragma unroll
        for (int ni = 0; ni < 4; ni++)
            bfr[ni] = *(const bf16x8*)(Bsub + (wc * 4 + ni) * 512 + l4 * 128 + l15 * 8);
#pragma unroll
        for (int mi = 0; mi < 4; mi++)
#pragma unroll
            for (int ni = 0; ni < 4; ni++)
                acc[mi][ni] = __builtin_amdgcn_mfma_f32_16x16x32_bf16(
                    af[mi], bfr[ni], acc[mi][ni], 0, 0, 0);
        __syncthreads();
    }

#pragma unroll
    for (int ni = 0; ni < 4; ni++) {
        int c = bn + wc * 64 + ni * 16 + l15;
        float bv = bias ? bias[c] : 0.f;
#pragma unroll
        for (int mi = 0; mi < 4; mi++) {
            int r0 = bm + wr * 64 + mi * 16 + l4 * 4;
#pragma unroll
            for (int e = 0; e < 4; e++)
                C[(long)(r0 + e) * ldc + c] = acc[mi][ni][e] * scale + bv;
        }
    }
}

// ---------------------------------------------------------------------------
// fp32 q-projection SGEMM with fused bias + BatchNorm epilogue.
// q = BN(x @ wq^T + bq).  M=N=K=1024.  64x64 tile, BK=32, 4x4/thread,
// float4 LDS fragment reads, prefetched staging.
// ---------------------------------------------------------------------------
__global__ __launch_bounds__(256) void sgemm_qproj(
    const float* __restrict__ A, const float* __restrict__ W,
    float* __restrict__ Q,
    const float* __restrict__ bq, const float* __restrict__ bn_w,
    const float* __restrict__ bn_b, const float* __restrict__ bn_mean,
    const float* __restrict__ bn_var)
{
    int bm = blockIdx.y * 64, bn = blockIdx.x * 64;
    __shared__ float As[32][64];
    __shared__ float Bs[32][64];
    int tid = threadIdx.x;
    int tx = tid & 15, ty = tid >> 4;
    int r = tid >> 2, q4 = tid & 3;
    float acc[4][4] = {{0.f}};

    const float* ga = A + (long)(bm + r) * 1024 + q4 * 8;
    const float* gb = W + (long)(bn + r) * 1024 + q4 * 8;

    float4 a0 = *(const float4*)(ga);
    float4 a1 = *(const float4*)(ga + 4);
    float4 b0 = *(const float4*)(gb);
    float4 b1 = *(const float4*)(gb + 4);

    for (int k0 = 0; k0 < 1024; k0 += 32) {
        __syncthreads();
        As[q4 * 8 + 0][r] = a0.x; As[q4 * 8 + 1][r] = a0.y;
        As[q4 * 8 + 2][r] = a0.z; As[q4 * 8 + 3][r] = a0.w;
        As[q4 * 8 + 4][r] = a1.x; As[q4 * 8 + 5][r] = a1.y;
        As[q4 * 8 + 6][r] = a1.z; As[q4 * 8 + 7][r] = a1.w;
        Bs[q4 * 8 + 0][r] = b0.x; Bs[q4 * 8 + 1][r] = b0.y;
        Bs[q4 * 8 + 2][r] = b0.z; Bs[q4 * 8 + 3][r] = b0.w;
        Bs[q4 * 8 + 4][r] = b1.x; Bs[q4 * 8 + 5][r] = b1.y;
        Bs[q4 * 8 + 6][r] = b1.z; Bs[q4 * 8 + 7][r] = b1.w;
        if (k0 + 32 < 1024) {
            a0 = *(const float4*)(ga + k0 + 32);
            a1 = *(const float4*)(ga + k0 + 36);
            b0 = *(const float4*)(gb + k0 + 32);
            b1 = *(const float4*)(gb + k0 + 36);
        }
        __syncthreads();
#pragma unroll
        for (int kk = 0; kk < 32; kk++) {
            float4 av = *(const float4*)&As[kk][ty * 4];
            float4 bv = *(const float4*)&Bs[kk][tx * 4];
            float a[4] = {av.x, av.y, av.z, av.w};
            float b[4] = {bv.x, bv.y, bv.z, bv.w};
#pragma unroll
            for (int i = 0; i < 4; i++)
#pragma unroll
                for (int j = 0; j < 4; j++)
                    acc[i][j] = fmaf(a[i], b[j], acc[i][j]);
        }
    }

#pragma unroll
    for (int j = 0; j < 4; j++) {
        int n = bn + tx * 4 + j;
        float s = rsqrtf(bn_var[n] + 1e-5f) * bn_w[n];
        float base = bq[n] - bn_mean[n];
        float bb = bn_b[n];
#pragma unroll
        for (int i = 0; i < 4; i++) {
            long m = bm + ty * 4 + i;
            Q[m * 1024 + n] = (acc[i][j] + base) * s + bb;
        }
    }
}

// ---------------------------------------------------------------------------
// va^T: vat[z][n][k] = va[b][k][h*128+n], z=b*8+h
// ---------------------------------------------------------------------------
__global__ __launch_bounds__(256) void transpose_va(
    const float* __restrict__ qkv, float* __restrict__ vat)
{
    int z = blockIdx.z;
    int b = z >> 3, h = z & 7;
    int k0 = blockIdx.x * 32, n0 = blockIdx.y * 32;
    __shared__ float tile[32][33];
    int tx = threadIdx.x & 31, ty = threadIdx.x >> 5;
    const float* src = qkv + 2048 + (long)b * 1572864 + (long)h * 128;
#pragma unroll
    for (int i = 0; i < 4; i++)
        tile[ty + 8 * i][tx] = src[(long)(k0 + ty + 8 * i) * 3072 + n0 + tx];
    __syncthreads();
    float* dst = vat + (long)z * 65536;
#pragma unroll
    for (int i = 0; i < 4; i++)
        dst[(long)(n0 + ty + 8 * i) * 512 + k0 + tx] = tile[tx][ty + 8 * i];
}

// ---------------------------------------------------------------------------
// Fused PEER, rank-based selection (fp32 exact selection path)
// launch_bounds(128,8): force VGPR<=64 for 8 waves/SIMD.
// ---------------------------------------------------------------------------
__global__ __launch_bounds__(128, 8) void peer_kernel(
    const float* __restrict__ q,        // (8192,128)
    const float* __restrict__ sub_keys, // (2,128,64)
    const float* __restrict__ ew,       // (16384,128)
    float* __restrict__ out)            // (8192,128)
{
    int th = blockIdx.x;
    int tid = threadIdx.x;

    __shared__ __align__(16) float qrow[128];
    __shared__ __align__(16) float s1s[128];
    __shared__ __align__(16) float s2s[128];
    __shared__ __align__(16) float tv1[16];
    __shared__ __align__(16) float tv2[16];
    __shared__ __align__(16) int   ti1[16];
    __shared__ __align__(16) int   ti2[16];
    __shared__ int   part[100];
    __shared__ int   eid[16];
    __shared__ float simv[16];
    __shared__ float rw[16];

    qrow[tid] = q[(long)th * 128 + tid];
    __syncthreads();

    // A: sub-key scores
    {
        const float4* k1 = (const float4*)(sub_keys + tid * 64);
        const float4* k2 = (const float4*)(sub_keys + 8192 + tid * 64);
        float a1 = 0.f, a2 = 0.f;
#pragma unroll 4
        for (int c = 0; c < 16; c++) {
            float4 v1 = k1[c], v2 = k2[c];
            a1 = fmaf(qrow[4 * c + 0], v1.x, a1);
            a1 = fmaf(qrow[4 * c + 1], v1.y, a1);
            a1 = fmaf(qrow[4 * c + 2], v1.z, a1);
            a1 = fmaf(qrow[4 * c + 3], v1.w, a1);
            a2 = fmaf(qrow[64 + 4 * c + 0], v2.x, a2);
            a2 = fmaf(qrow[64 + 4 * c + 1], v2.y, a2);
            a2 = fmaf(qrow[64 + 4 * c + 2], v2.z, a2);
            a2 = fmaf(qrow[64 + 4 * c + 3], v2.w, a2);
        }
        s1s[tid] = a1;
        s2s[tid] = a2;
    }
    __syncthreads();

    // B: parallel rank among 128 (descending, ties -> lower index)
    {
        float m1 = s1s[tid], m2 = s2s[tid];
        int r1 = 0, r2 = 0;
        for (int j = 0; j < 128; j += 4) {
            float4 a = *(const float4*)&s1s[j];
            float4 b = *(const float4*)&s2s[j];
            r1 += (a.x > m1) || (a.x == m1 && j + 0 < tid);
            r1 += (a.y > m1) || (a.y == m1 && j + 1 < tid);
            r1 += (a.z > m1) || (a.z == m1 && j + 2 < tid);
            r1 += (a.w > m1) || (a.w == m1 && j + 3 < tid);
            r2 += (b.x > m2) || (b.x == m2 && j + 0 < tid);
            r2 += (b.y > m2) || (b.y == m2 && j + 1 < tid);
            r2 += (b.z > m2) || (b.z == m2 && j + 2 < tid);
            r2 += (b.w > m2) || (b.w == m2 && j + 3 < tid);
        }
        if (r1 < 16) { tv1[r1] = m1; ti1[r1] = tid; }
        if (r2 < 16) { tv2[r2] = m2; ti2[r2] = tid; }
    }
    __syncthreads();

    // C: candidate top-16 over the 50-elem staircase {(i,j):(i+1)(j+1)<=16}
    if (tid < 100) {
        int c = tid >> 1, h = tid & 1;
        int i, j;
        if      (c < 16) { i = 0; j = c; }
        else if (c < 24) { i = 1; j = c - 16; }
        else if (c < 29) { i = 2; j = c - 24; }
        else if (c < 33) { i = 3; j = c - 29; }
        else if (c < 36) { i = 4; j = c - 33; }
        else if (c < 38) { i = 5; j = c - 36; }
        else if (c < 40) { i = 6; j = c - 38; }
        else if (c < 42) { i = 7; j = c - 40; }
        else             { i = 8 + (c - 42); j = 0; }
        float val = tv1[i] + tv2[j];
        int myid = ti1[i] * 128 + ti2[j];
        int cnt = 0;
        for (int ip = h * 8; ip < h * 8 + 8; ip++) {
            float a = tv1[ip];
            int ia = ti1[ip] * 128;
            for (int jp = 0; jp < 16; jp += 4) {
                float4 v4 = *(const float4*)&tv2[jp];
                int4 id4 = *(const int4*)&ti2[jp];
                cnt += (a + v4.x > val) || (a + v4.x == val && ia + id4.x < myid);
                cnt += (a + v4.y > val) || (a + v4.y == val && ia + id4.y < myid);
                cnt += (a + v4.z > val) || (a + v4.z == val && ia + id4.z < myid);
                cnt += (a + v4.w > val) || (a + v4.w == val && ia + id4.w < myid);
            }
        }
        part[tid] = cnt;
    }
    __syncthreads();
    if (tid < 50) {
        int r = part[2 * tid] + part[2 * tid + 1];
        if (r < 16) {
            int c = tid;
            int i, j;
            if      (c < 16) { i = 0; j = c; }
            else if (c < 24) { i = 1; j = c - 16; }
            else if (c < 29) { i = 2; j = c - 24; }
            else if (c < 33) { i = 3; j = c - 29; }
            else if (c < 36) { i = 4; j = c - 33; }
            else if (c < 38) { i = 5; j = c - 36; }
            else if (c < 40) { i = 6; j = c - 38; }
            else if (c < 42) { i = 7; j = c - 40; }
            else             { i = 8 + (c - 42); j = 0; }
            eid[r] = ti1[i] * 128 + ti2[j];
        }
    }
    __syncthreads();

    // D: sim via 8 threads per expert + shuffle reduce
    {
        int e = tid >> 3, g = tid & 7;
        const float4* e4 = (const float4*)(ew + (long)eid[e] * 128 + g * 16);
        const float* qb = qrow + g * 16;
        float acc = 0.f;
#pragma unroll 2
        for (int m = 0; m < 4; m++) {
            float4 v = e4[m];
            acc = fmaf(qb[4 * m + 0], v.x, acc);
            acc = fmaf(qb[4 * m + 1], v.y, acc);
            acc = fmaf(qb[4 * m + 2], v.z, acc);
            acc = fmaf(qb[4 * m + 3], v.w, acc);
        }
        acc += __shfl_down(acc, 4);
        acc += __shfl_down(acc, 2);
        acc += __shfl_down(acc, 1);
        if (g == 0) simv[e] = acc;
    }
    __syncthreads();

    if (tid < 16) {
        float mx = simv[0];
#pragma unroll
        for (int k = 1; k < 16; k++) mx = fmaxf(mx, simv[k]);
        rw[tid] = expf(simv[tid] - mx);
    }
    __syncthreads();

    {
        float wsum = 0.f;
#pragma unroll
        for (int k = 0; k < 16; k++) wsum += rw[k];
        float inv = 1.f / wsum;
        float o = 0.f;
#pragma unroll
        for (int k = 0; k < 16; k++)
            o = fmaf(rw[k], ew[(long)eid[k] * 128 + tid], o);
        out[(long)th * 128 + tid] = o * inv;
    }
}

// ---------------------------------------------------------------------------
// Fused attention softmax + head-mean.
// Block = (b,row): 256 threads, 4 waves. Wave w softmaxes head rows w and w+4
// (512 cols, 8 floats/lane, shfl reductions), writes back to att, accumulates
// into its msum slice; then 4 slices are reduced to the mean output.
// ---------------------------------------------------------------------------
__global__ __launch_bounds__(256) void softmax_mean(
    float* __restrict__ att, float* __restrict__ outw)
{
    int blk = blockIdx.x;          // b*512 + row
    int b = blk >> 9, row = blk & 511;
    int tid = threadIdx.x;
    int w = tid >> 6, lane = tid & 63;

    __shared__ float msum[4][512];

#pragma unroll
    for (int pass = 0; pass < 2; pass++) {
        int h = w + pass * 4;
        long base = ((long)(b * 8 + h) * 512 + row) * 512 + lane * 8;
        float4 v0 = *(const float4*)(att + base);
        float4 v1 = *(const float4*)(att + base + 4);
        float m = fmaxf(fmaxf(fmaxf(v0.x, v0.y), fmaxf(v0.z, v0.w)),
                        fmaxf(fmaxf(v1.x, v1.y), fmaxf(v1.z, v1.w)));
#pragma unroll
        for (int off = 32; off > 0; off >>= 1)
            m = fmaxf(m, __shfl_xor(m, off));
        float e[8];
        e[0] = expf(v0.x - m); e[1] = expf(v0.y - m);
        e[2] = expf(v0.z - m); e[3] = expf(v0.w - m);
        e[4] = expf(v1.x - m); e[5] = expf(v1.y - m);
        e[6] = expf(v1.z - m); e[7] = expf(v1.w - m);
        float s = e[0] + e[1] + e[2] + e[3] + e[4] + e[5] + e[6] + e[7];
#pragma unroll
        for (int off = 32; off > 0; off >>= 1)
            s += __shfl_xor(s, off);
        float inv = 1.f / s;
        float4 p0 = make_float4(e[0] * inv, e[1] * inv, e[2] * inv, e[3] * inv);
        float4 p1 = make_float4(e[4] * inv, e[5] * inv, e[6] * inv, e[7] * inv);
        *(float4*)(att + base) = p0;
        *(float4*)(att + base + 4) = p1;
        int c = lane * 8;
        if (pass == 0) {
            msum[w][c + 0] = p0.x; msum[w][c + 1] = p0.y;
            msum[w][c + 2] = p0.z; msum[w][c + 3] = p0.w;
            msum[w][c + 4] = p1.x; msum[w][c + 5] = p1.y;
            msum[w][c + 6] = p1.z; msum[w][c + 7] = p1.w;
        } else {
            msum[w][c + 0] += p0.x; msum[w][c + 1] += p0.y;
            msum[w][c + 2] += p0.z; msum[w][c + 3] += p0.w;
            msum[w][c + 4] += p1.x; msum[w][c + 5] += p1.y;
            msum[w][c + 6] += p1.z; msum[w][c + 7] += p1.w;
        }
    }
    __syncthreads();
#pragma unroll
    for (int i = 0; i < 2; i++) {
        int c = tid + i * 256;
        float s = (msum[0][c] + msum[1][c] + msum[2][c] + msum[3][c]) * 0.125f;
        outw[(long)blk * 512 + c] = s;
    }
}

// ---------------------------------------------------------------------------
__global__ __launch_bounds__(256) void final_fuse(
    const float* __restrict__ x, const float* __restrict__ out2,
    const float* __restrict__ ao2, const float* __restrict__ rms_w,
    float* __restrict__ y)
{
    long base = (long)blockIdx.x * 1024;
    int tid = threadIdx.x;
    float v[4];
    float ss = 0.f;
#pragma unroll
    for (int i = 0; i < 4; i++) {
        int d = tid + i * 256;
        v[i] = x[base + d] + out2[base + d] + ao2[base + d];
        ss = fmaf(v[i], v[i], ss);
    }
    __shared__ float red[256];
    red[tid] = ss;
    __syncthreads();
    for (int st = 128; st > 0; st >>= 1) {
        if (tid < st) red[tid] += red[tid + st];
        __syncthreads();
    }
    float scale = rsqrtf(red[0] * (1.f / 1024.f) + 1e-6f);
#pragma unroll
    for (int i = 0; i < 4; i++) {
        int d = tid + i * 256;
        y[base + d] = v[i] * scale * rms_w[d];
    }
}

// ---------------------------------------------------------------------------
extern "C" void kernel_launch(void* const* d_in, const int* in_sizes, int n_in,
                              void* d_out, int out_size, void* d_ws, size_t ws_size,
                              hipStream_t stream)
{
    const float* x         = (const float*)d_in[0];
    const float* wq        = (const float*)d_in[1];
    const float* bq        = (const float*)d_in[2];
    const float* bn_w      = (const float*)d_in[3];
    const float* bn_b      = (const float*)d_in[4];
    const float* bn_mean   = (const float*)d_in[5];
    const float* bn_var    = (const float*)d_in[6];
    const float* sub_keys  = (const float*)d_in[7];
    const float* ew        = (const float*)d_in[8];
    const float* wo        = (const float*)d_in[9];
    const float* bo        = (const float*)d_in[10];
    const float* in_proj_w = (const float*)d_in[11];
    const float* in_proj_b = (const float*)d_in[12];
    const float* attn_ow   = (const float*)d_in[13];
    const float* attn_ob   = (const float*)d_in[14];
    const float* rms_w     = (const float*)d_in[15];
    float* out = (float*)d_out;

    float* ws   = (float*)d_ws;
    float* q    = ws;                 // 1024x1024 (dead after peer; reused as vat)
    float* peer = ws + 1048576;       // 1024x1024
    float* out2 = ws + 2097152;       // 1024x1024
    float* qkv  = ws + 3145728;       // 1024x3072
    float* att  = ws + 6291456;       // 16x512x512
    float* ao   = ws + 10485760;      // 1024x1024
    float* ao2  = ws + 11534336;      // 1024x1024
    float* vat  = q;                  // 16x128x512 (aliases q)

    dim3 blk(256);

    // 1. q = BN(x @ wq^T + bq)   (fp32 exact, BN fused)
    sgemm_qproj<<<dim3(16, 16, 1), blk, 0, stream>>>(
        x, wq, q, bq, bn_w, bn_b, bn_mean, bn_var);

    // 2. PEER
    peer_kernel<<<8192, 128, 0, stream>>>(q, sub_keys, ew, peer);

    // 3. out2 = peer @ wo^T + bo  (MFMA)
    gemm_mfma<<<dim3(8, 8, 1), blk, 0, stream>>>(
        peer, 1024L, 0L, 0L, wo, 1024L, 0L, 0L, out2, 1024L, 0L, 0L,
        1024, bo, 1.0f, 1);

    // 4. qkv = x @ in_proj^T + b  (MFMA)
    gemm_mfma<<<dim3(24, 8, 1), blk, 0, stream>>>(
        x, 1024L, 0L, 0L, in_proj_w, 1024L, 0L, 0L, qkv, 3072L, 0L, 0L,
        1024, in_proj_b, 1.0f, 1);

    // 5. vat = va^T (q's slot is free now)
    transpose_va<<<dim3(16, 4, 16), blk, 0, stream>>>(qkv, vat);

    // 6. att scores = qa @ ka^T / sqrt(128)  (MFMA)
    gemm_mfma<<<dim3(4, 4, 16), blk, 0, stream>>>(
        qkv, 3072L, 1572864L, 128L,
        qkv + 1024, 3072L, 1572864L, 128L,
        att, 512L, 2097152L, 262144L,
        128, nullptr, 0.08838834764831845f, 8);

    // 7. softmax + head-mean fused; mean -> out[1048576:]
    softmax_mean<<<1024, 256, 0, stream>>>(att, out + 1048576);

    // 8. ao = att @ vat^T  (MFMA)
    gemm_mfma<<<dim3(1, 4, 16), blk, 0, stream>>>(
        att, 512L, 2097152L, 262144L,
        vat, 512L, 524288L, 65536L,
        ao, 1024L, 524288L, 128L,
        512, nullptr, 1.0f, 8);

    // 9. ao2 = ao @ attn_ow^T + attn_ob  (MFMA)
    gemm_mfma<<<dim3(8, 8, 1), blk, 0, stream>>>(
        ao, 1024L, 0L, 0L, attn_ow, 1024L, 0L, 0L, ao2, 1024L, 0L, 0L,
        1024, attn_ob, 1.0f, 1);

    // 10. final fuse -> out[0:1048576]
    final_fuse<<<1024, 256, 0, stream>>>(x, out2, ao2, rms_w, out);
}

// Round 6
// 431.673 us; speedup vs baseline: 1.3569x; 1.3569x over previous
//
#include <hip/hip_runtime.h>
#include <hip/hip_bf16.h>
#include <math.h>

#define NEG_INF -3.0e38f

typedef __attribute__((ext_vector_type(8))) short bf16x8;
typedef __attribute__((ext_vector_type(4))) float f32x4;

__device__ inline short f2bf(float f) {
    __hip_bfloat16 h = __float2bfloat16(f);
    return *reinterpret_cast<short*>(&h);
}

// ---------------------------------------------------------------------------
// bf16 MFMA GEMM: C[m][n] = scale * sum_k A[m][k]*B[n][k] (+bias[n])
// 128x128 tile, 4 waves, BK=32, mfma_f32_16x16x32_bf16.
// ---------------------------------------------------------------------------
__global__ __launch_bounds__(256) void gemm_mfma(
    const float* __restrict__ A, long lda, long sAb, long sAh,
    const float* __restrict__ B, long ldb, long sBb, long sBh,
    float* __restrict__ C, long ldc, long sCb, long sCh,
    int K, const float* __restrict__ bias, float scale, int hDiv)
{
    int bz = blockIdx.z;
    int bb = bz / hDiv, hh = bz % hDiv;
    A += bb * sAb + hh * sAh;
    B += bb * sBb + hh * sBh;
    C += bb * sCb + hh * sCh;
    int bm = blockIdx.y * 128, bn = blockIdx.x * 128;

    __shared__ __align__(16) short Asub[4096];
    __shared__ __align__(16) short Bsub[4096];

    int tid = threadIdx.x;
    int lane = tid & 63;
    int wave = tid >> 6;
    int wr = wave >> 1, wc = wave & 1;
    int l15 = lane & 15, l4 = lane >> 4;

    f32x4 acc[4][4] = {};

    int sr = tid >> 1;
    int sh = tid & 1;
    const float* gA = A + (long)(bm + sr) * lda + sh * 16;
    const float* gB = B + (long)(bn + sr) * ldb + sh * 16;
    short* wA = Asub + (sr >> 4) * 512 + (sr & 15) * 8 + sh * 256;
    short* wB = Bsub + (sr >> 4) * 512 + (sr & 15) * 8 + sh * 256;

    for (int k0 = 0; k0 < K; k0 += 32) {
        float4 a0 = *(const float4*)(gA + k0);
        float4 a1 = *(const float4*)(gA + k0 + 4);
        float4 a2 = *(const float4*)(gA + k0 + 8);
        float4 a3 = *(const float4*)(gA + k0 + 12);
        float4 b0 = *(const float4*)(gB + k0);
        float4 b1 = *(const float4*)(gB + k0 + 4);
        float4 b2 = *(const float4*)(gB + k0 + 8);
        float4 b3 = *(const float4*)(gB + k0 + 12);
        bf16x8 ua0, ua1, ub0, ub1;
        ua0[0]=f2bf(a0.x); ua0[1]=f2bf(a0.y); ua0[2]=f2bf(a0.z); ua0[3]=f2bf(a0.w);
        ua0[4]=f2bf(a1.x); ua0[5]=f2bf(a1.y); ua0[6]=f2bf(a1.z); ua0[7]=f2bf(a1.w);
        ua1[0]=f2bf(a2.x); ua1[1]=f2bf(a2.y); ua1[2]=f2bf(a2.z); ua1[3]=f2bf(a2.w);
        ua1[4]=f2bf(a3.x); ua1[5]=f2bf(a3.y); ua1[6]=f2bf(a3.z); ua1[7]=f2bf(a3.w);
        ub0[0]=f2bf(b0.x); ub0[1]=f2bf(b0.y); ub0[2]=f2bf(b0.z); ub0[3]=f2bf(b0.w);
        ub0[4]=f2bf(b1.x); ub0[5]=f2bf(b1.y); ub0[6]=f2bf(b1.z); ub0[7]=f2bf(b1.w);
        ub1[0]=f2bf(b2.x); ub1[1]=f2bf(b2.y); ub1[2]=f2bf(b2.z); ub1[3]=f2bf(b2.w);
        ub1[4]=f2bf(b3.x); ub1[5]=f2bf(b3.y); ub1[6]=f2bf(b3.z); ub1[7]=f2bf(b3.w);
        *(bf16x8*)wA = ua0;
        *(bf16x8*)(wA + 128) = ua1;
        *(bf16x8*)wB = ub0;
        *(bf16x8*)(wB + 128) = ub1;
        __syncthreads();

        bf16x8 af[4], bfr[4];
#pragma unroll
        for (int mi = 0; mi < 4; mi++)
            af[mi] = *(const bf16x8*)(Asub + (wr * 4 + mi) * 512 + l4 * 128 + l15 * 8);
#pragma unroll
        for (int ni = 0; ni < 4; ni++)
            bfr[ni] = *(const bf16x8*)(Bsub + (wc * 4 + ni) * 512 + l4 * 128 + l15 * 8);
#pragma unroll
        for (int mi = 0; mi < 4; mi++)
#pragma unroll
            for (int ni = 0; ni < 4; ni++)
                acc[mi][ni] = __builtin_amdgcn_mfma_f32_16x16x32_bf16(
                    af[mi], bfr[ni], acc[mi][ni], 0, 0, 0);
        __syncthreads();
    }

#pragma unroll
    for (int ni = 0; ni < 4; ni++) {
        int c = bn + wc * 64 + ni * 16 + l15;
        float bv = bias ? bias[c] : 0.f;
#pragma unroll
        for (int mi = 0; mi < 4; mi++) {
            int r0 = bm + wr * 64 + mi * 16 + l4 * 4;
#pragma unroll
            for (int e = 0; e < 4; e++)
                C[(long)(r0 + e) * ldc + c] = acc[mi][ni][e] * scale + bv;
        }
    }
}

// ---------------------------------------------------------------------------
// fp32 q-projection SGEMM with fused bias + BatchNorm epilogue.
// ---------------------------------------------------------------------------
__global__ __launch_bounds__(256) void sgemm_qproj(
    const float* __restrict__ A, const float* __restrict__ W,
    float* __restrict__ Q,
    const float* __restrict__ bq, const float* __restrict__ bn_w,
    const float* __restrict__ bn_b, const float* __restrict__ bn_mean,
    const float* __restrict__ bn_var)
{
    int bm = blockIdx.y * 64, bn = blockIdx.x * 64;
    __shared__ float As[32][64];
    __shared__ float Bs[32][64];
    int tid = threadIdx.x;
    int tx = tid & 15, ty = tid >> 4;
    int r = tid >> 2, q4 = tid & 3;
    float acc[4][4] = {{0.f}};

    const float* ga = A + (long)(bm + r) * 1024 + q4 * 8;
    const float* gb = W + (long)(bn + r) * 1024 + q4 * 8;

    float4 a0 = *(const float4*)(ga);
    float4 a1 = *(const float4*)(ga + 4);
    float4 b0 = *(const float4*)(gb);
    float4 b1 = *(const float4*)(gb + 4);

    for (int k0 = 0; k0 < 1024; k0 += 32) {
        __syncthreads();
        As[q4 * 8 + 0][r] = a0.x; As[q4 * 8 + 1][r] = a0.y;
        As[q4 * 8 + 2][r] = a0.z; As[q4 * 8 + 3][r] = a0.w;
        As[q4 * 8 + 4][r] = a1.x; As[q4 * 8 + 5][r] = a1.y;
        As[q4 * 8 + 6][r] = a1.z; As[q4 * 8 + 7][r] = a1.w;
        Bs[q4 * 8 + 0][r] = b0.x; Bs[q4 * 8 + 1][r] = b0.y;
        Bs[q4 * 8 + 2][r] = b0.z; Bs[q4 * 8 + 3][r] = b0.w;
        Bs[q4 * 8 + 4][r] = b1.x; Bs[q4 * 8 + 5][r] = b1.y;
        Bs[q4 * 8 + 6][r] = b1.z; Bs[q4 * 8 + 7][r] = b1.w;
        if (k0 + 32 < 1024) {
            a0 = *(const float4*)(ga + k0 + 32);
            a1 = *(const float4*)(ga + k0 + 36);
            b0 = *(const float4*)(gb + k0 + 32);
            b1 = *(const float4*)(gb + k0 + 36);
        }
        __syncthreads();
#pragma unroll
        for (int kk = 0; kk < 32; kk++) {
            float4 av = *(const float4*)&As[kk][ty * 4];
            float4 bv = *(const float4*)&Bs[kk][tx * 4];
            float a[4] = {av.x, av.y, av.z, av.w};
            float b[4] = {bv.x, bv.y, bv.z, bv.w};
#pragma unroll
            for (int i = 0; i < 4; i++)
#pragma unroll
                for (int j = 0; j < 4; j++)
                    acc[i][j] = fmaf(a[i], b[j], acc[i][j]);
        }
    }

#pragma unroll
    for (int j = 0; j < 4; j++) {
        int n = bn + tx * 4 + j;
        float s = rsqrtf(bn_var[n] + 1e-5f) * bn_w[n];
        float base = bq[n] - bn_mean[n];
        float bb = bn_b[n];
#pragma unroll
        for (int i = 0; i < 4; i++) {
            long m = bm + ty * 4 + i;
            Q[m * 1024 + n] = (acc[i][j] + base) * s + bb;
        }
    }
}

// ---------------------------------------------------------------------------
// va^T: vat[z][n][k] = va[b][k][h*128+n], z=b*8+h
// ---------------------------------------------------------------------------
__global__ __launch_bounds__(256) void transpose_va(
    const float* __restrict__ qkv, float* __restrict__ vat)
{
    int z = blockIdx.z;
    int b = z >> 3, h = z & 7;
    int k0 = blockIdx.x * 32, n0 = blockIdx.y * 32;
    __shared__ float tile[32][33];
    int tx = threadIdx.x & 31, ty = threadIdx.x >> 5;
    const float* src = qkv + 2048 + (long)b * 1572864 + (long)h * 128;
#pragma unroll
    for (int i = 0; i < 4; i++)
        tile[ty + 8 * i][tx] = src[(long)(k0 + ty + 8 * i) * 3072 + n0 + tx];
    __syncthreads();
    float* dst = vat + (long)z * 65536;
#pragma unroll
    for (int i = 0; i < 4; i++)
        dst[(long)(n0 + ty + 8 * i) * 512 + k0 + tx] = tile[tx][ty + 8 * i];
}

// ---------------------------------------------------------------------------
// Fused PEER, rank-based selection (fp32 exact selection path)
// Plain __launch_bounds__(128): natural VGPR (~84), no spills.
// ---------------------------------------------------------------------------
__global__ __launch_bounds__(128) void peer_kernel(
    const float* __restrict__ q,        // (8192,128)
    const float* __restrict__ sub_keys, // (2,128,64)
    const float* __restrict__ ew,       // (16384,128)
    float* __restrict__ out)            // (8192,128)
{
    int th = blockIdx.x;
    int tid = threadIdx.x;

    __shared__ __align__(16) float qrow[128];
    __shared__ __align__(16) float s1s[128];
    __shared__ __align__(16) float s2s[128];
    __shared__ __align__(16) float tv1[16];
    __shared__ __align__(16) float tv2[16];
    __shared__ __align__(16) int   ti1[16];
    __shared__ __align__(16) int   ti2[16];
    __shared__ int   part[100];
    __shared__ int   eid[16];
    __shared__ float simv[16];
    __shared__ float rw[16];

    qrow[tid] = q[(long)th * 128 + tid];
    __syncthreads();

    // A: sub-key scores
    {
        const float4* k1 = (const float4*)(sub_keys + tid * 64);
        const float4* k2 = (const float4*)(sub_keys + 8192 + tid * 64);
        float a1 = 0.f, a2 = 0.f;
#pragma unroll 4
        for (int c = 0; c < 16; c++) {
            float4 v1 = k1[c], v2 = k2[c];
            a1 = fmaf(qrow[4 * c + 0], v1.x, a1);
            a1 = fmaf(qrow[4 * c + 1], v1.y, a1);
            a1 = fmaf(qrow[4 * c + 2], v1.z, a1);
            a1 = fmaf(qrow[4 * c + 3], v1.w, a1);
            a2 = fmaf(qrow[64 + 4 * c + 0], v2.x, a2);
            a2 = fmaf(qrow[64 + 4 * c + 1], v2.y, a2);
            a2 = fmaf(qrow[64 + 4 * c + 2], v2.z, a2);
            a2 = fmaf(qrow[64 + 4 * c + 3], v2.w, a2);
        }
        s1s[tid] = a1;
        s2s[tid] = a2;
    }
    __syncthreads();

    // B: parallel rank among 128 (descending, ties -> lower index)
    {
        float m1 = s1s[tid], m2 = s2s[tid];
        int r1 = 0, r2 = 0;
        for (int j = 0; j < 128; j += 4) {
            float4 a = *(const float4*)&s1s[j];
            float4 b = *(const float4*)&s2s[j];
            r1 += (a.x > m1) || (a.x == m1 && j + 0 < tid);
            r1 += (a.y > m1) || (a.y == m1 && j + 1 < tid);
            r1 += (a.z > m1) || (a.z == m1 && j + 2 < tid);
            r1 += (a.w > m1) || (a.w == m1 && j + 3 < tid);
            r2 += (b.x > m2) || (b.x == m2 && j + 0 < tid);
            r2 += (b.y > m2) || (b.y == m2 && j + 1 < tid);
            r2 += (b.z > m2) || (b.z == m2 && j + 2 < tid);
            r2 += (b.w > m2) || (b.w == m2 && j + 3 < tid);
        }
        if (r1 < 16) { tv1[r1] = m1; ti1[r1] = tid; }
        if (r2 < 16) { tv2[r2] = m2; ti2[r2] = tid; }
    }
    __syncthreads();

    // C: candidate top-16 over the 50-elem staircase {(i,j):(i+1)(j+1)<=16}
    if (tid < 100) {
        int c = tid >> 1, h = tid & 1;
        int i, j;
        if      (c < 16) { i = 0; j = c; }
        else if (c < 24) { i = 1; j = c - 16; }
        else if (c < 29) { i = 2; j = c - 24; }
        else if (c < 33) { i = 3; j = c - 29; }
        else if (c < 36) { i = 4; j = c - 33; }
        else if (c < 38) { i = 5; j = c - 36; }
        else if (c < 40) { i = 6; j = c - 38; }
        else if (c < 42) { i = 7; j = c - 40; }
        else             { i = 8 + (c - 42); j = 0; }
        float val = tv1[i] + tv2[j];
        int myid = ti1[i] * 128 + ti2[j];
        int cnt = 0;
        for (int ip = h * 8; ip < h * 8 + 8; ip++) {
            float a = tv1[ip];
            int ia = ti1[ip] * 128;
            for (int jp = 0; jp < 16; jp += 4) {
                float4 v4 = *(const float4*)&tv2[jp];
                int4 id4 = *(const int4*)&ti2[jp];
                cnt += (a + v4.x > val) || (a + v4.x == val && ia + id4.x < myid);
                cnt += (a + v4.y > val) || (a + v4.y == val && ia + id4.y < myid);
                cnt += (a + v4.z > val) || (a + v4.z == val && ia + id4.z < myid);
                cnt += (a + v4.w > val) || (a + v4.w == val && ia + id4.w < myid);
            }
        }
        part[tid] = cnt;
    }
    __syncthreads();
    if (tid < 50) {
        int r = part[2 * tid] + part[2 * tid + 1];
        if (r < 16) {
            int c = tid;
            int i, j;
            if      (c < 16) { i = 0; j = c; }
            else if (c < 24) { i = 1; j = c - 16; }
            else if (c < 29) { i = 2; j = c - 24; }
            else if (c < 33) { i = 3; j = c - 29; }
            else if (c < 36) { i = 4; j = c - 33; }
            else if (c < 38) { i = 5; j = c - 36; }
            else if (c < 40) { i = 6; j = c - 38; }
            else if (c < 42) { i = 7; j = c - 40; }
            else             { i = 8 + (c - 42); j = 0; }
            eid[r] = ti1[i] * 128 + ti2[j];
        }
    }
    __syncthreads();

    // D: sim via 8 threads per expert + shuffle reduce
    {
        int e = tid >> 3, g = tid & 7;
        const float4* e4 = (const float4*)(ew + (long)eid[e] * 128 + g * 16);
        const float* qb = qrow + g * 16;
        float acc = 0.f;
#pragma unroll 2
        for (int m = 0; m < 4; m++) {
            float4 v = e4[m];
            acc = fmaf(qb[4 * m + 0], v.x, acc);
            acc = fmaf(qb[4 * m + 1], v.y, acc);
            acc = fmaf(qb[4 * m + 2], v.z, acc);
            acc = fmaf(qb[4 * m + 3], v.w, acc);
        }
        acc += __shfl_down(acc, 4);
        acc += __shfl_down(acc, 2);
        acc += __shfl_down(acc, 1);
        if (g == 0) simv[e] = acc;
    }
    __syncthreads();

    if (tid < 16) {
        float mx = simv[0];
#pragma unroll
        for (int k = 1; k < 16; k++) mx = fmaxf(mx, simv[k]);
        rw[tid] = expf(simv[tid] - mx);
    }
    __syncthreads();

    {
        float wsum = 0.f;
#pragma unroll
        for (int k = 0; k < 16; k++) wsum += rw[k];
        float inv = 1.f / wsum;
        float o = 0.f;
#pragma unroll
        for (int k = 0; k < 16; k++)
            o = fmaf(rw[k], ew[(long)eid[k] * 128 + tid], o);
        out[(long)th * 128 + tid] = o * inv;
    }
}

// ---------------------------------------------------------------------------
// Fused attention softmax + head-mean.
// ---------------------------------------------------------------------------
__global__ __launch_bounds__(256) void softmax_mean(
    float* __restrict__ att, float* __restrict__ outw)
{
    int blk = blockIdx.x;          // b*512 + row
    int b = blk >> 9, row = blk & 511;
    int tid = threadIdx.x;
    int w = tid >> 6, lane = tid & 63;

    __shared__ float msum[4][516];   // 516: break stride-8 bank aliasing

#pragma unroll
    for (int pass = 0; pass < 2; pass++) {
        int h = w + pass * 4;
        long base = ((long)(b * 8 + h) * 512 + row) * 512 + lane * 8;
        float4 v0 = *(const float4*)(att + base);
        float4 v1 = *(const float4*)(att + base + 4);
        float m = fmaxf(fmaxf(fmaxf(v0.x, v0.y), fmaxf(v0.z, v0.w)),
                        fmaxf(fmaxf(v1.x, v1.y), fmaxf(v1.z, v1.w)));
#pragma unroll
        for (int off = 32; off > 0; off >>= 1)
            m = fmaxf(m, __shfl_xor(m, off));
        float e[8];
        e[0] = expf(v0.x - m); e[1] = expf(v0.y - m);
        e[2] = expf(v0.z - m); e[3] = expf(v0.w - m);
        e[4] = expf(v1.x - m); e[5] = expf(v1.y - m);
        e[6] = expf(v1.z - m); e[7] = expf(v1.w - m);
        float s = e[0] + e[1] + e[2] + e[3] + e[4] + e[5] + e[6] + e[7];
#pragma unroll
        for (int off = 32; off > 0; off >>= 1)
            s += __shfl_xor(s, off);
        float inv = 1.f / s;
        float4 p0 = make_float4(e[0] * inv, e[1] * inv, e[2] * inv, e[3] * inv);
        float4 p1 = make_float4(e[4] * inv, e[5] * inv, e[6] * inv, e[7] * inv);
        *(float4*)(att + base) = p0;
        *(float4*)(att + base + 4) = p1;
        int c = lane * 8;
        if (pass == 0) {
            msum[w][c + 0] = p0.x; msum[w][c + 1] = p0.y;
            msum[w][c + 2] = p0.z; msum[w][c + 3] = p0.w;
            msum[w][c + 4] = p1.x; msum[w][c + 5] = p1.y;
            msum[w][c + 6] = p1.z; msum[w][c + 7] = p1.w;
        } else {
            msum[w][c + 0] += p0.x; msum[w][c + 1] += p0.y;
            msum[w][c + 2] += p0.z; msum[w][c + 3] += p0.w;
            msum[w][c + 4] += p1.x; msum[w][c + 5] += p1.y;
            msum[w][c + 6] += p1.z; msum[w][c + 7] += p1.w;
        }
    }
    __syncthreads();
#pragma unroll
    for (int i = 0; i < 2; i++) {
        int c = tid + i * 256;
        float s = (msum[0][c] + msum[1][c] + msum[2][c] + msum[3][c]) * 0.125f;
        outw[(long)blk * 512 + c] = s;
    }
}

// ---------------------------------------------------------------------------
__global__ __launch_bounds__(256) void final_fuse(
    const float* __restrict__ x, const float* __restrict__ out2,
    const float* __restrict__ ao2, const float* __restrict__ rms_w,
    float* __restrict__ y)
{
    long base = (long)blockIdx.x * 1024;
    int tid = threadIdx.x;
    float v[4];
    float ss = 0.f;
#pragma unroll
    for (int i = 0; i < 4; i++) {
        int d = tid + i * 256;
        v[i] = x[base + d] + out2[base + d] + ao2[base + d];
        ss = fmaf(v[i], v[i], ss);
    }
    __shared__ float red[256];
    red[tid] = ss;
    __syncthreads();
    for (int st = 128; st > 0; st >>= 1) {
        if (tid < st) red[tid] += red[tid + st];
        __syncthreads();
    }
    float scale = rsqrtf(red[0] * (1.f / 1024.f) + 1e-6f);
#pragma unroll
    for (int i = 0; i < 4; i++) {
        int d = tid + i * 256;
        y[base + d] = v[i] * scale * rms_w[d];
    }
}

// ---------------------------------------------------------------------------
extern "C" void kernel_launch(void* const* d_in, const int* in_sizes, int n_in,
                              void* d_out, int out_size, void* d_ws, size_t ws_size,
                              hipStream_t stream)
{
    const float* x         = (const float*)d_in[0];
    const float* wq        = (const float*)d_in[1];
    const float* bq        = (const float*)d_in[2];
    const float* bn_w      = (const float*)d_in[3];
    const float* bn_b      = (const float*)d_in[4];
    const float* bn_mean   = (const float*)d_in[5];
    const float* bn_var    = (const float*)d_in[6];
    const float* sub_keys  = (const float*)d_in[7];
    const float* ew        = (const float*)d_in[8];
    const float* wo        = (const float*)d_in[9];
    const float* bo        = (const float*)d_in[10];
    const float* in_proj_w = (const float*)d_in[11];
    const float* in_proj_b = (const float*)d_in[12];
    const float* attn_ow   = (const float*)d_in[13];
    const float* attn_ob   = (const float*)d_in[14];
    const float* rms_w     = (const float*)d_in[15];
    float* out = (float*)d_out;

    float* ws   = (float*)d_ws;
    float* q    = ws;                 // 1024x1024 (dead after peer; reused as vat)
    float* peer = ws + 1048576;       // 1024x1024
    float* out2 = ws + 2097152;       // 1024x1024
    float* qkv  = ws + 3145728;       // 1024x3072
    float* att  = ws + 6291456;       // 16x512x512
    float* ao   = ws + 10485760;      // 1024x1024
    float* ao2  = ws + 11534336;      // 1024x1024
    float* vat  = q;                  // 16x128x512 (aliases q)

    dim3 blk(256);

    // 1. q = BN(x @ wq^T + bq)   (fp32 exact, BN fused)
    sgemm_qproj<<<dim3(16, 16, 1), blk, 0, stream>>>(
        x, wq, q, bq, bn_w, bn_b, bn_mean, bn_var);

    // 2. PEER
    peer_kernel<<<8192, 128, 0, stream>>>(q, sub_keys, ew, peer);

    // 3. out2 = peer @ wo^T + bo  (MFMA)
    gemm_mfma<<<dim3(8, 8, 1), blk, 0, stream>>>(
        peer, 1024L, 0L, 0L, wo, 1024L, 0L, 0L, out2, 1024L, 0L, 0L,
        1024, bo, 1.0f, 1);

    // 4. qkv = x @ in_proj^T + b  (MFMA)
    gemm_mfma<<<dim3(24, 8, 1), blk, 0, stream>>>(
        x, 1024L, 0L, 0L, in_proj_w, 1024L, 0L, 0L, qkv, 3072L, 0L, 0L,
        1024, in_proj_b, 1.0f, 1);

    // 5. vat = va^T (q's slot is free now)
    transpose_va<<<dim3(16, 4, 16), blk, 0, stream>>>(qkv, vat);

    // 6. att scores = qa @ ka^T / sqrt(128)  (MFMA)
    gemm_mfma<<<dim3(4, 4, 16), blk, 0, stream>>>(
        qkv, 3072L, 1572864L, 128L,
        qkv + 1024, 3072L, 1572864L, 128L,
        att, 512L, 2097152L, 262144L,
        128, nullptr, 0.08838834764831845f, 8);

    // 7. softmax + head-mean fused; mean -> out[1048576:]
    softmax_mean<<<1024, 256, 0, stream>>>(att, out + 1048576);

    // 8. ao = att @ vat^T  (MFMA)
    gemm_mfma<<<dim3(1, 4, 16), blk, 0, stream>>>(
        att, 512L, 2097152L, 262144L,
        vat, 512L, 524288L, 65536L,
        ao, 1024L, 524288L, 128L,
        512, nullptr, 1.0f, 8);

    // 9. ao2 = ao @ attn_ow^T + attn_ob  (MFMA)
    gemm_mfma<<<dim3(8, 8, 1), blk, 0, stream>>>(
        ao, 1024L, 0L, 0L, attn_ow, 1024L, 0L, 0L, ao2, 1024L, 0L, 0L,
        1024, attn_ob, 1.0f, 1);

    // 10. final fuse -> out[0:1048576]
    final_fuse<<<1024, 256, 0, stream>>>(x, out2, ao2, rms_w, out);
}

// Round 7
// 377.182 us; speedup vs baseline: 1.5529x; 1.1445x over previous
//
#include <hip/hip_runtime.h>
#include <hip/hip_bf16.h>
#include <math.h>

typedef __attribute__((ext_vector_type(8))) short bf16x8;
typedef __attribute__((ext_vector_type(4))) float f32x4;

__device__ inline short f2bf(float f) {
    __hip_bfloat16 h = __float2bfloat16(f);
    return *reinterpret_cast<short*>(&h);
}

// ---------------------------------------------------------------------------
// bf16 MFMA GEMM, 64x64 tile / 256 threads / 4 waves (one 32x32 per wave).
// C[m][n] = scale * sum_k A[m][k]*B[n][k] (+bias[n]).  K mult of 32.
// Grid: (N/64, M/64, batch). Small tile => >=256 blocks for all our GEMMs.
// LDS subtile layout (16 rows x 32 k, 1KB): off = kgrp*128 + (row&15)*8 shorts.
// ---------------------------------------------------------------------------
__global__ __launch_bounds__(256) void gemm_mfma64(
    const float* __restrict__ A, long lda, long sAb, long sAh,
    const float* __restrict__ B, long ldb, long sBb, long sBh,
    float* __restrict__ C, long ldc, long sCb, long sCh,
    int K, const float* __restrict__ bias, float scale, int hDiv)
{
    int bz = blockIdx.z;
    int bb = bz / hDiv, hh = bz % hDiv;
    A += bb * sAb + hh * sAh;
    B += bb * sBb + hh * sBh;
    C += bb * sCb + hh * sCh;
    int bm = blockIdx.y * 64, bn = blockIdx.x * 64;

    __shared__ __align__(16) short Asub[2048];
    __shared__ __align__(16) short Bsub[2048];

    int tid = threadIdx.x;
    int lane = tid & 63;
    int wave = tid >> 6;
    int wr = wave >> 1, wc = wave & 1;
    int l15 = lane & 15, l4 = lane >> 4;

    f32x4 acc[2][2] = {};

    int sr = tid >> 2;   // row 0..63
    int sq = tid & 3;    // kgroup (8 floats)
    const float* gA = A + (long)(bm + sr) * lda + sq * 8;
    const float* gB = B + (long)(bn + sr) * ldb + sq * 8;
    short* wA = Asub + (sr >> 4) * 512 + sq * 128 + (sr & 15) * 8;
    short* wB = Bsub + (sr >> 4) * 512 + sq * 128 + (sr & 15) * 8;

    for (int k0 = 0; k0 < K; k0 += 32) {
        float4 a0 = *(const float4*)(gA + k0);
        float4 a1 = *(const float4*)(gA + k0 + 4);
        float4 b0 = *(const float4*)(gB + k0);
        float4 b1 = *(const float4*)(gB + k0 + 4);
        bf16x8 ua, ub;
        ua[0]=f2bf(a0.x); ua[1]=f2bf(a0.y); ua[2]=f2bf(a0.z); ua[3]=f2bf(a0.w);
        ua[4]=f2bf(a1.x); ua[5]=f2bf(a1.y); ua[6]=f2bf(a1.z); ua[7]=f2bf(a1.w);
        ub[0]=f2bf(b0.x); ub[1]=f2bf(b0.y); ub[2]=f2bf(b0.z); ub[3]=f2bf(b0.w);
        ub[4]=f2bf(b1.x); ub[5]=f2bf(b1.y); ub[6]=f2bf(b1.z); ub[7]=f2bf(b1.w);
        *(bf16x8*)wA = ua;
        *(bf16x8*)wB = ub;
        __syncthreads();

        bf16x8 af[2], bfr[2];
#pragma unroll
        for (int mi = 0; mi < 2; mi++)
            af[mi] = *(const bf16x8*)(Asub + (wr * 2 + mi) * 512 + l4 * 128 + l15 * 8);
#pragma unroll
        for (int ni = 0; ni < 2; ni++)
            bfr[ni] = *(const bf16x8*)(Bsub + (wc * 2 + ni) * 512 + l4 * 128 + l15 * 8);
#pragma unroll
        for (int mi = 0; mi < 2; mi++)
#pragma unroll
            for (int ni = 0; ni < 2; ni++)
                acc[mi][ni] = __builtin_amdgcn_mfma_f32_16x16x32_bf16(
                    af[mi], bfr[ni], acc[mi][ni], 0, 0, 0);
        __syncthreads();
    }

#pragma unroll
    for (int ni = 0; ni < 2; ni++) {
        int c = bn + wc * 32 + ni * 16 + l15;
        float bv = bias ? bias[c] : 0.f;
#pragma unroll
        for (int mi = 0; mi < 2; mi++) {
            int r0 = bm + wr * 32 + mi * 16 + l4 * 4;
#pragma unroll
            for (int e = 0; e < 4; e++)
                C[(long)(r0 + e) * ldc + c] = acc[mi][ni][e] * scale + bv;
        }
    }
}

// ---------------------------------------------------------------------------
// fp32 q-projection SGEMM with fused bias + BatchNorm epilogue.
// ---------------------------------------------------------------------------
__global__ __launch_bounds__(256) void sgemm_qproj(
    const float* __restrict__ A, const float* __restrict__ W,
    float* __restrict__ Q,
    const float* __restrict__ bq, const float* __restrict__ bn_w,
    const float* __restrict__ bn_b, const float* __restrict__ bn_mean,
    const float* __restrict__ bn_var)
{
    int bm = blockIdx.y * 64, bn = blockIdx.x * 64;
    __shared__ float As[32][64];
    __shared__ float Bs[32][64];
    int tid = threadIdx.x;
    int tx = tid & 15, ty = tid >> 4;
    int r = tid >> 2, q4 = tid & 3;
    float acc[4][4] = {{0.f}};

    const float* ga = A + (long)(bm + r) * 1024 + q4 * 8;
    const float* gb = W + (long)(bn + r) * 1024 + q4 * 8;

    float4 a0 = *(const float4*)(ga);
    float4 a1 = *(const float4*)(ga + 4);
    float4 b0 = *(const float4*)(gb);
    float4 b1 = *(const float4*)(gb + 4);

    for (int k0 = 0; k0 < 1024; k0 += 32) {
        __syncthreads();
        As[q4 * 8 + 0][r] = a0.x; As[q4 * 8 + 1][r] = a0.y;
        As[q4 * 8 + 2][r] = a0.z; As[q4 * 8 + 3][r] = a0.w;
        As[q4 * 8 + 4][r] = a1.x; As[q4 * 8 + 5][r] = a1.y;
        As[q4 * 8 + 6][r] = a1.z; As[q4 * 8 + 7][r] = a1.w;
        Bs[q4 * 8 + 0][r] = b0.x; Bs[q4 * 8 + 1][r] = b0.y;
        Bs[q4 * 8 + 2][r] = b0.z; Bs[q4 * 8 + 3][r] = b0.w;
        Bs[q4 * 8 + 4][r] = b1.x; Bs[q4 * 8 + 5][r] = b1.y;
        Bs[q4 * 8 + 6][r] = b1.z; Bs[q4 * 8 + 7][r] = b1.w;
        if (k0 + 32 < 1024) {
            a0 = *(const float4*)(ga + k0 + 32);
            a1 = *(const float4*)(ga + k0 + 36);
            b0 = *(const float4*)(gb + k0 + 32);
            b1 = *(const float4*)(gb + k0 + 36);
        }
        __syncthreads();
#pragma unroll
        for (int kk = 0; kk < 32; kk++) {
            float4 av = *(const float4*)&As[kk][ty * 4];
            float4 bv = *(const float4*)&Bs[kk][tx * 4];
            float a[4] = {av.x, av.y, av.z, av.w};
            float b[4] = {bv.x, bv.y, bv.z, bv.w};
#pragma unroll
            for (int i = 0; i < 4; i++)
#pragma unroll
                for (int j = 0; j < 4; j++)
                    acc[i][j] = fmaf(a[i], b[j], acc[i][j]);
        }
    }

#pragma unroll
    for (int j = 0; j < 4; j++) {
        int n = bn + tx * 4 + j;
        float s = rsqrtf(bn_var[n] + 1e-5f) * bn_w[n];
        float base = bq[n] - bn_mean[n];
        float bb = bn_b[n];
#pragma unroll
        for (int i = 0; i < 4; i++) {
            long m = bm + ty * 4 + i;
            Q[m * 1024 + n] = (acc[i][j] + base) * s + bb;
        }
    }
}

// ---------------------------------------------------------------------------
// va^T: vat[z][n][k] = va[b][k][h*128+n], z=b*8+h
// ---------------------------------------------------------------------------
__global__ __launch_bounds__(256) void transpose_va(
    const float* __restrict__ qkv, float* __restrict__ vat)
{
    int z = blockIdx.z;
    int b = z >> 3, h = z & 7;
    int k0 = blockIdx.x * 32, n0 = blockIdx.y * 32;
    __shared__ float tile[32][33];
    int tx = threadIdx.x & 31, ty = threadIdx.x >> 5;
    const float* src = qkv + 2048 + (long)b * 1572864 + (long)h * 128;
#pragma unroll
    for (int i = 0; i < 4; i++)
        tile[ty + 8 * i][tx] = src[(long)(k0 + ty + 8 * i) * 3072 + n0 + tx];
    __syncthreads();
    float* dst = vat + (long)z * 65536;
#pragma unroll
    for (int i = 0; i < 4; i++)
        dst[(long)(n0 + ty + 8 * i) * 512 + k0 + tx] = tile[tx][ty + 8 * i];
}

// ---------------------------------------------------------------------------
// Fused PEER, rank-based selection (fp32 exact selection path)
// ---------------------------------------------------------------------------
__global__ __launch_bounds__(128) void peer_kernel(
    const float* __restrict__ q,        // (8192,128)
    const float* __restrict__ sub_keys, // (2,128,64)
    const float* __restrict__ ew,       // (16384,128)
    float* __restrict__ out)            // (8192,128)
{
    int th = blockIdx.x;
    int tid = threadIdx.x;

    __shared__ __align__(16) float qrow[128];
    __shared__ __align__(16) float s1s[128];
    __shared__ __align__(16) float s2s[128];
    __shared__ __align__(16) float tv1[16];
    __shared__ __align__(16) float tv2[16];
    __shared__ __align__(16) int   ti1[16];
    __shared__ __align__(16) int   ti2[16];
    __shared__ int   part[100];
    __shared__ int   eid[16];
    __shared__ float simv[16];
    __shared__ float rw[16];

    qrow[tid] = q[(long)th * 128 + tid];
    __syncthreads();

    // A: sub-key scores
    {
        const float4* k1 = (const float4*)(sub_keys + tid * 64);
        const float4* k2 = (const float4*)(sub_keys + 8192 + tid * 64);
        float a1 = 0.f, a2 = 0.f;
#pragma unroll 4
        for (int c = 0; c < 16; c++) {
            float4 v1 = k1[c], v2 = k2[c];
            a1 = fmaf(qrow[4 * c + 0], v1.x, a1);
            a1 = fmaf(qrow[4 * c + 1], v1.y, a1);
            a1 = fmaf(qrow[4 * c + 2], v1.z, a1);
            a1 = fmaf(qrow[4 * c + 3], v1.w, a1);
            a2 = fmaf(qrow[64 + 4 * c + 0], v2.x, a2);
            a2 = fmaf(qrow[64 + 4 * c + 1], v2.y, a2);
            a2 = fmaf(qrow[64 + 4 * c + 2], v2.z, a2);
            a2 = fmaf(qrow[64 + 4 * c + 3], v2.w, a2);
        }
        s1s[tid] = a1;
        s2s[tid] = a2;
    }
    __syncthreads();

    // B: parallel rank among 128 (descending, ties -> lower index)
    {
        float m1 = s1s[tid], m2 = s2s[tid];
        int r1 = 0, r2 = 0;
        for (int j = 0; j < 128; j += 4) {
            float4 a = *(const float4*)&s1s[j];
            float4 b = *(const float4*)&s2s[j];
            r1 += (a.x > m1) || (a.x == m1 && j + 0 < tid);
            r1 += (a.y > m1) || (a.y == m1 && j + 1 < tid);
            r1 += (a.z > m1) || (a.z == m1 && j + 2 < tid);
            r1 += (a.w > m1) || (a.w == m1 && j + 3 < tid);
            r2 += (b.x > m2) || (b.x == m2 && j + 0 < tid);
            r2 += (b.y > m2) || (b.y == m2 && j + 1 < tid);
            r2 += (b.z > m2) || (b.z == m2 && j + 2 < tid);
            r2 += (b.w > m2) || (b.w == m2 && j + 3 < tid);
        }
        if (r1 < 16) { tv1[r1] = m1; ti1[r1] = tid; }
        if (r2 < 16) { tv2[r2] = m2; ti2[r2] = tid; }
    }
    __syncthreads();

    // C: candidate top-16 over the 50-elem staircase {(i,j):(i+1)(j+1)<=16}
    if (tid < 100) {
        int c = tid >> 1, h = tid & 1;
        int i, j;
        if      (c < 16) { i = 0; j = c; }
        else if (c < 24) { i = 1; j = c - 16; }
        else if (c < 29) { i = 2; j = c - 24; }
        else if (c < 33) { i = 3; j = c - 29; }
        else if (c < 36) { i = 4; j = c - 33; }
        else if (c < 38) { i = 5; j = c - 36; }
        else if (c < 40) { i = 6; j = c - 38; }
        else if (c < 42) { i = 7; j = c - 40; }
        else             { i = 8 + (c - 42); j = 0; }
        float val = tv1[i] + tv2[j];
        int myid = ti1[i] * 128 + ti2[j];
        int cnt = 0;
        for (int ip = h * 8; ip < h * 8 + 8; ip++) {
            float a = tv1[ip];
            int ia = ti1[ip] * 128;
            for (int jp = 0; jp < 16; jp += 4) {
                float4 v4 = *(const float4*)&tv2[jp];
                int4 id4 = *(const int4*)&ti2[jp];
                cnt += (a + v4.x > val) || (a + v4.x == val && ia + id4.x < myid);
                cnt += (a + v4.y > val) || (a + v4.y == val && ia + id4.y < myid);
                cnt += (a + v4.z > val) || (a + v4.z == val && ia + id4.z < myid);
                cnt += (a + v4.w > val) || (a + v4.w == val && ia + id4.w < myid);
            }
        }
        part[tid] = cnt;
    }
    __syncthreads();
    if (tid < 50) {
        int r = part[2 * tid] + part[2 * tid + 1];
        if (r < 16) {
            int c = tid;
            int i, j;
            if      (c < 16) { i = 0; j = c; }
            else if (c < 24) { i = 1; j = c - 16; }
            else if (c < 29) { i = 2; j = c - 24; }
            else if (c < 33) { i = 3; j = c - 29; }
            else if (c < 36) { i = 4; j = c - 33; }
            else if (c < 38) { i = 5; j = c - 36; }
            else if (c < 40) { i = 6; j = c - 38; }
            else if (c < 42) { i = 7; j = c - 40; }
            else             { i = 8 + (c - 42); j = 0; }
            eid[r] = ti1[i] * 128 + ti2[j];
        }
    }
    __syncthreads();

    // D: sim via 8 threads per expert + shuffle reduce
    {
        int e = tid >> 3, g = tid & 7;
        const float4* e4 = (const float4*)(ew + (long)eid[e] * 128 + g * 16);
        const float* qb = qrow + g * 16;
        float acc = 0.f;
#pragma unroll 2
        for (int m = 0; m < 4; m++) {
            float4 v = e4[m];
            acc = fmaf(qb[4 * m + 0], v.x, acc);
            acc = fmaf(qb[4 * m + 1], v.y, acc);
            acc = fmaf(qb[4 * m + 2], v.z, acc);
            acc = fmaf(qb[4 * m + 3], v.w, acc);
        }
        acc += __shfl_down(acc, 4);
        acc += __shfl_down(acc, 2);
        acc += __shfl_down(acc, 1);
        if (g == 0) simv[e] = acc;
    }
    __syncthreads();

    if (tid < 16) {
        float mx = simv[0];
#pragma unroll
        for (int k = 1; k < 16; k++) mx = fmaxf(mx, simv[k]);
        rw[tid] = expf(simv[tid] - mx);
    }
    __syncthreads();

    {
        float wsum = 0.f;
#pragma unroll
        for (int k = 0; k < 16; k++) wsum += rw[k];
        float inv = 1.f / wsum;
        float o = 0.f;
#pragma unroll
        for (int k = 0; k < 16; k++)
            o = fmaf(rw[k], ew[(long)eid[k] * 128 + tid], o);
        out[(long)th * 128 + tid] = o * inv;
    }
}

// ---------------------------------------------------------------------------
// Fused attention softmax + head-mean.
// ---------------------------------------------------------------------------
__global__ __launch_bounds__(256) void softmax_mean(
    float* __restrict__ att, float* __restrict__ outw)
{
    int blk = blockIdx.x;          // b*512 + row
    int b = blk >> 9, row = blk & 511;
    int tid = threadIdx.x;
    int w = tid >> 6, lane = tid & 63;

    __shared__ float msum[4][516];

#pragma unroll
    for (int pass = 0; pass < 2; pass++) {
        int h = w + pass * 4;
        long base = ((long)(b * 8 + h) * 512 + row) * 512 + lane * 8;
        float4 v0 = *(const float4*)(att + base);
        float4 v1 = *(const float4*)(att + base + 4);
        float m = fmaxf(fmaxf(fmaxf(v0.x, v0.y), fmaxf(v0.z, v0.w)),
                        fmaxf(fmaxf(v1.x, v1.y), fmaxf(v1.z, v1.w)));
#pragma unroll
        for (int off = 32; off > 0; off >>= 1)
            m = fmaxf(m, __shfl_xor(m, off));
        float e[8];
        e[0] = expf(v0.x - m); e[1] = expf(v0.y - m);
        e[2] = expf(v0.z - m); e[3] = expf(v0.w - m);
        e[4] = expf(v1.x - m); e[5] = expf(v1.y - m);
        e[6] = expf(v1.z - m); e[7] = expf(v1.w - m);
        float s = e[0] + e[1] + e[2] + e[3] + e[4] + e[5] + e[6] + e[7];
#pragma unroll
        for (int off = 32; off > 0; off >>= 1)
            s += __shfl_xor(s, off);
        float inv = 1.f / s;
        float4 p0 = make_float4(e[0] * inv, e[1] * inv, e[2] * inv, e[3] * inv);
        float4 p1 = make_float4(e[4] * inv, e[5] * inv, e[6] * inv, e[7] * inv);
        *(float4*)(att + base) = p0;
        *(float4*)(att + base + 4) = p1;
        int c = lane * 8;
        if (pass == 0) {
            msum[w][c + 0] = p0.x; msum[w][c + 1] = p0.y;
            msum[w][c + 2] = p0.z; msum[w][c + 3] = p0.w;
            msum[w][c + 4] = p1.x; msum[w][c + 5] = p1.y;
            msum[w][c + 6] = p1.z; msum[w][c + 7] = p1.w;
        } else {
            msum[w][c + 0] += p0.x; msum[w][c + 1] += p0.y;
            msum[w][c + 2] += p0.z; msum[w][c + 3] += p0.w;
            msum[w][c + 4] += p1.x; msum[w][c + 5] += p1.y;
            msum[w][c + 6] += p1.z; msum[w][c + 7] += p1.w;
        }
    }
    __syncthreads();
#pragma unroll
    for (int i = 0; i < 2; i++) {
        int c = tid + i * 256;
        float s = (msum[0][c] + msum[1][c] + msum[2][c] + msum[3][c]) * 0.125f;
        outw[(long)blk * 512 + c] = s;
    }
}

// ---------------------------------------------------------------------------
__global__ __launch_bounds__(256) void final_fuse(
    const float* __restrict__ x, const float* __restrict__ out2,
    const float* __restrict__ ao2, const float* __restrict__ rms_w,
    float* __restrict__ y)
{
    long base = (long)blockIdx.x * 1024;
    int tid = threadIdx.x;
    float v[4];
    float ss = 0.f;
#pragma unroll
    for (int i = 0; i < 4; i++) {
        int d = tid + i * 256;
        v[i] = x[base + d] + out2[base + d] + ao2[base + d];
        ss = fmaf(v[i], v[i], ss);
    }
    __shared__ float red[256];
    red[tid] = ss;
    __syncthreads();
    for (int st = 128; st > 0; st >>= 1) {
        if (tid < st) red[tid] += red[tid + st];
        __syncthreads();
    }
    float scale = rsqrtf(red[0] * (1.f / 1024.f) + 1e-6f);
#pragma unroll
    for (int i = 0; i < 4; i++) {
        int d = tid + i * 256;
        y[base + d] = v[i] * scale * rms_w[d];
    }
}

// ---------------------------------------------------------------------------
extern "C" void kernel_launch(void* const* d_in, const int* in_sizes, int n_in,
                              void* d_out, int out_size, void* d_ws, size_t ws_size,
                              hipStream_t stream)
{
    const float* x         = (const float*)d_in[0];
    const float* wq        = (const float*)d_in[1];
    const float* bq        = (const float*)d_in[2];
    const float* bn_w      = (const float*)d_in[3];
    const float* bn_b      = (const float*)d_in[4];
    const float* bn_mean   = (const float*)d_in[5];
    const float* bn_var    = (const float*)d_in[6];
    const float* sub_keys  = (const float*)d_in[7];
    const float* ew        = (const float*)d_in[8];
    const float* wo        = (const float*)d_in[9];
    const float* bo        = (const float*)d_in[10];
    const float* in_proj_w = (const float*)d_in[11];
    const float* in_proj_b = (const float*)d_in[12];
    const float* attn_ow   = (const float*)d_in[13];
    const float* attn_ob   = (const float*)d_in[14];
    const float* rms_w     = (const float*)d_in[15];
    float* out = (float*)d_out;

    float* ws   = (float*)d_ws;
    float* q    = ws;                 // 1024x1024 (dead after peer; reused as vat)
    float* peer = ws + 1048576;       // 1024x1024
    float* out2 = ws + 2097152;       // 1024x1024
    float* qkv  = ws + 3145728;       // 1024x3072
    float* att  = ws + 6291456;       // 16x512x512
    float* ao   = ws + 10485760;      // 1024x1024
    float* ao2  = ws + 11534336;      // 1024x1024
    float* vat  = q;                  // 16x128x512 (aliases q)

    dim3 blk(256);

    // 1. q = BN(x @ wq^T + bq)   (fp32 exact, BN fused)
    sgemm_qproj<<<dim3(16, 16, 1), blk, 0, stream>>>(
        x, wq, q, bq, bn_w, bn_b, bn_mean, bn_var);

    // 2. PEER
    peer_kernel<<<8192, 128, 0, stream>>>(q, sub_keys, ew, peer);

    // 3. out2 = peer @ wo^T + bo   (256 blocks)
    gemm_mfma64<<<dim3(16, 16, 1), blk, 0, stream>>>(
        peer, 1024L, 0L, 0L, wo, 1024L, 0L, 0L, out2, 1024L, 0L, 0L,
        1024, bo, 1.0f, 1);

    // 4. qkv = x @ in_proj^T + b   (768 blocks)
    gemm_mfma64<<<dim3(48, 16, 1), blk, 0, stream>>>(
        x, 1024L, 0L, 0L, in_proj_w, 1024L, 0L, 0L, qkv, 3072L, 0L, 0L,
        1024, in_proj_b, 1.0f, 1);

    // 5. vat = va^T (q's slot is free now)
    transpose_va<<<dim3(16, 4, 16), blk, 0, stream>>>(qkv, vat);

    // 6. att scores = qa @ ka^T / sqrt(128)   (1024 blocks)
    gemm_mfma64<<<dim3(8, 8, 16), blk, 0, stream>>>(
        qkv, 3072L, 1572864L, 128L,
        qkv + 1024, 3072L, 1572864L, 128L,
        att, 512L, 2097152L, 262144L,
        128, nullptr, 0.08838834764831845f, 8);

    // 7. softmax + head-mean fused; mean -> out[1048576:]
    softmax_mean<<<1024, 256, 0, stream>>>(att, out + 1048576);

    // 8. ao = att @ vat^T   (256 blocks)
    gemm_mfma64<<<dim3(2, 8, 16), blk, 0, stream>>>(
        att, 512L, 2097152L, 262144L,
        vat, 512L, 524288L, 65536L,
        ao, 1024L, 524288L, 128L,
        512, nullptr, 1.0f, 8);

    // 9. ao2 = ao @ attn_ow^T + attn_ob   (256 blocks)
    gemm_mfma64<<<dim3(16, 16, 1), blk, 0, stream>>>(
        ao, 1024L, 0L, 0L, attn_ow, 1024L, 0L, 0L, ao2, 1024L, 0L, 0L,
        1024, attn_ob, 1.0f, 1);

    // 10. final fuse -> out[0:1048576]
    final_fuse<<<1024, 256, 0, stream>>>(x, out2, ao2, rms_w, out);
}

// Round 8
// 335.943 us; speedup vs baseline: 1.7435x; 1.1228x over previous
//
#include <hip/hip_runtime.h>
#include <hip/hip_bf16.h>
#include <math.h>

typedef __attribute__((ext_vector_type(8))) short bf16x8;
typedef __attribute__((ext_vector_type(4))) float f32x4;

__device__ inline short f2bf(float f) {
    __hip_bfloat16 h = __float2bfloat16(f);
    return *reinterpret_cast<short*>(&h);
}

// order-preserving float -> uint map (strictly monotone for non-NaN)
__device__ inline unsigned int obits(float f) {
    unsigned int u = __float_as_uint(f);
    return (u & 0x80000000u) ? ~u : (u | 0x80000000u);
}

// ---------------------------------------------------------------------------
// bf16 MFMA GEMM, 64x64 tile / 256 threads / 4 waves, reg-staged with
// next-K-step prefetch (1 block/CU regime -> ILP is the only latency hider).
// C[m][n] = scale * sum_k A[m][k]*B[n][k] (+bias[n]).  K mult of 32.
// ---------------------------------------------------------------------------
__global__ __launch_bounds__(256) void gemm_mfma64(
    const float* __restrict__ A, long lda, long sAb, long sAh,
    const float* __restrict__ B, long ldb, long sBb, long sBh,
    float* __restrict__ C, long ldc, long sCb, long sCh,
    int K, const float* __restrict__ bias, float scale, int hDiv)
{
    int bz = blockIdx.z;
    int bb = bz / hDiv, hh = bz % hDiv;
    A += bb * sAb + hh * sAh;
    B += bb * sBb + hh * sBh;
    C += bb * sCb + hh * sCh;
    int bm = blockIdx.y * 64, bn = blockIdx.x * 64;

    __shared__ __align__(16) short Asub[2048];
    __shared__ __align__(16) short Bsub[2048];

    int tid = threadIdx.x;
    int lane = tid & 63;
    int wave = tid >> 6;
    int wr = wave >> 1, wc = wave & 1;
    int l15 = lane & 15, l4 = lane >> 4;

    f32x4 acc[2][2] = {};

    int sr = tid >> 2;   // row 0..63
    int sq = tid & 3;    // kgroup (8 floats)
    const float* gA = A + (long)(bm + sr) * lda + sq * 8;
    const float* gB = B + (long)(bn + sr) * ldb + sq * 8;
    short* wA = Asub + (sr >> 4) * 512 + sq * 128 + (sr & 15) * 8;
    short* wB = Bsub + (sr >> 4) * 512 + sq * 128 + (sr & 15) * 8;

    float4 a0 = *(const float4*)(gA);
    float4 a1 = *(const float4*)(gA + 4);
    float4 b0 = *(const float4*)(gB);
    float4 b1 = *(const float4*)(gB + 4);

    for (int k0 = 0; k0 < K; k0 += 32) {
        bf16x8 ua, ub;
        ua[0]=f2bf(a0.x); ua[1]=f2bf(a0.y); ua[2]=f2bf(a0.z); ua[3]=f2bf(a0.w);
        ua[4]=f2bf(a1.x); ua[5]=f2bf(a1.y); ua[6]=f2bf(a1.z); ua[7]=f2bf(a1.w);
        ub[0]=f2bf(b0.x); ub[1]=f2bf(b0.y); ub[2]=f2bf(b0.z); ub[3]=f2bf(b0.w);
        ub[4]=f2bf(b1.x); ub[5]=f2bf(b1.y); ub[6]=f2bf(b1.z); ub[7]=f2bf(b1.w);
        *(bf16x8*)wA = ua;
        *(bf16x8*)wB = ub;
        __syncthreads();

        if (k0 + 32 < K) {                    // prefetch next K-step early
            a0 = *(const float4*)(gA + k0 + 32);
            a1 = *(const float4*)(gA + k0 + 36);
            b0 = *(const float4*)(gB + k0 + 32);
            b1 = *(const float4*)(gB + k0 + 36);
        }

        bf16x8 af[2], bfr[2];
#pragma unroll
        for (int mi = 0; mi < 2; mi++)
            af[mi] = *(const bf16x8*)(Asub + (wr * 2 + mi) * 512 + l4 * 128 + l15 * 8);
#pragma unroll
        for (int ni = 0; ni < 2; ni++)
            bfr[ni] = *(const bf16x8*)(Bsub + (wc * 2 + ni) * 512 + l4 * 128 + l15 * 8);
#pragma unroll
        for (int mi = 0; mi < 2; mi++)
#pragma unroll
            for (int ni = 0; ni < 2; ni++)
                acc[mi][ni] = __builtin_amdgcn_mfma_f32_16x16x32_bf16(
                    af[mi], bfr[ni], acc[mi][ni], 0, 0, 0);
        __syncthreads();
    }

#pragma unroll
    for (int ni = 0; ni < 2; ni++) {
        int c = bn + wc * 32 + ni * 16 + l15;
        float bv = bias ? bias[c] : 0.f;
#pragma unroll
        for (int mi = 0; mi < 2; mi++) {
            int r0 = bm + wr * 32 + mi * 16 + l4 * 4;
#pragma unroll
            for (int e = 0; e < 4; e++)
                C[(long)(r0 + e) * ldc + c] = acc[mi][ni][e] * scale + bv;
        }
    }
}

// ---------------------------------------------------------------------------
// fp32 q-projection SGEMM with fused bias + BatchNorm epilogue.
// ---------------------------------------------------------------------------
__global__ __launch_bounds__(256) void sgemm_qproj(
    const float* __restrict__ A, const float* __restrict__ W,
    float* __restrict__ Q,
    const float* __restrict__ bq, const float* __restrict__ bn_w,
    const float* __restrict__ bn_b, const float* __restrict__ bn_mean,
    const float* __restrict__ bn_var)
{
    int bm = blockIdx.y * 64, bn = blockIdx.x * 64;
    __shared__ float As[32][64];
    __shared__ float Bs[32][64];
    int tid = threadIdx.x;
    int tx = tid & 15, ty = tid >> 4;
    int r = tid >> 2, q4 = tid & 3;
    float acc[4][4] = {{0.f}};

    const float* ga = A + (long)(bm + r) * 1024 + q4 * 8;
    const float* gb = W + (long)(bn + r) * 1024 + q4 * 8;

    float4 a0 = *(const float4*)(ga);
    float4 a1 = *(const float4*)(ga + 4);
    float4 b0 = *(const float4*)(gb);
    float4 b1 = *(const float4*)(gb + 4);

    for (int k0 = 0; k0 < 1024; k0 += 32) {
        __syncthreads();
        As[q4 * 8 + 0][r] = a0.x; As[q4 * 8 + 1][r] = a0.y;
        As[q4 * 8 + 2][r] = a0.z; As[q4 * 8 + 3][r] = a0.w;
        As[q4 * 8 + 4][r] = a1.x; As[q4 * 8 + 5][r] = a1.y;
        As[q4 * 8 + 6][r] = a1.z; As[q4 * 8 + 7][r] = a1.w;
        Bs[q4 * 8 + 0][r] = b0.x; Bs[q4 * 8 + 1][r] = b0.y;
        Bs[q4 * 8 + 2][r] = b0.z; Bs[q4 * 8 + 3][r] = b0.w;
        Bs[q4 * 8 + 4][r] = b1.x; Bs[q4 * 8 + 5][r] = b1.y;
        Bs[q4 * 8 + 6][r] = b1.z; Bs[q4 * 8 + 7][r] = b1.w;
        if (k0 + 32 < 1024) {
            a0 = *(const float4*)(ga + k0 + 32);
            a1 = *(const float4*)(ga + k0 + 36);
            b0 = *(const float4*)(gb + k0 + 32);
            b1 = *(const float4*)(gb + k0 + 36);
        }
        __syncthreads();
#pragma unroll
        for (int kk = 0; kk < 32; kk++) {
            float4 av = *(const float4*)&As[kk][ty * 4];
            float4 bv = *(const float4*)&Bs[kk][tx * 4];
            float a[4] = {av.x, av.y, av.z, av.w};
            float b[4] = {bv.x, bv.y, bv.z, bv.w};
#pragma unroll
            for (int i = 0; i < 4; i++)
#pragma unroll
                for (int j = 0; j < 4; j++)
                    acc[i][j] = fmaf(a[i], b[j], acc[i][j]);
        }
    }

#pragma unroll
    for (int j = 0; j < 4; j++) {
        int n = bn + tx * 4 + j;
        float s = rsqrtf(bn_var[n] + 1e-5f) * bn_w[n];
        float base = bq[n] - bn_mean[n];
        float bb = bn_b[n];
#pragma unroll
        for (int i = 0; i < 4; i++) {
            long m = bm + ty * 4 + i;
            Q[m * 1024 + n] = (acc[i][j] + base) * s + bb;
        }
    }
}

// ---------------------------------------------------------------------------
// va^T: vat[z][n][k] = va[b][k][h*128+n], z=b*8+h
// ---------------------------------------------------------------------------
__global__ __launch_bounds__(256) void transpose_va(
    const float* __restrict__ qkv, float* __restrict__ vat)
{
    int z = blockIdx.z;
    int b = z >> 3, h = z & 7;
    int k0 = blockIdx.x * 32, n0 = blockIdx.y * 32;
    __shared__ float tile[32][33];
    int tx = threadIdx.x & 31, ty = threadIdx.x >> 5;
    const float* src = qkv + 2048 + (long)b * 1572864 + (long)h * 128;
#pragma unroll
    for (int i = 0; i < 4; i++)
        tile[ty + 8 * i][tx] = src[(long)(k0 + ty + 8 * i) * 3072 + n0 + tx];
    __syncthreads();
    float* dst = vat + (long)z * 65536;
#pragma unroll
    for (int i = 0; i < 4; i++)
        dst[(long)(n0 + ty + 8 * i) * 512 + k0 + tx] = tile[tx][ty + 8 * i];
}

// ---------------------------------------------------------------------------
// Fused PEER v3: u64 compound-key ranking (val-orderedbits | inverted-index).
// Selection identical to reference stable top-k; one v_cmp_gt_u64 per compare.
// ---------------------------------------------------------------------------
__global__ __launch_bounds__(128) void peer_kernel(
    const float* __restrict__ q,        // (8192,128)
    const float* __restrict__ sub_keys, // (2,128,64)
    const float* __restrict__ ew,       // (16384,128)
    float* __restrict__ out)            // (8192,128)
{
    int th = blockIdx.x;
    int tid = threadIdx.x;

    __shared__ __align__(16) float qrow[128];
    __shared__ __align__(16) unsigned long long k1s[128];
    __shared__ __align__(16) unsigned long long k2s[128];
    __shared__ __align__(16) unsigned long long cks[256];
    __shared__ float tv1[16], tv2[16];
    __shared__ int   ti1[16], ti2[16];
    __shared__ int   part[100];
    __shared__ int   eid[16];
    __shared__ float simv[16];
    __shared__ float rw[16];

    qrow[tid] = q[(long)th * 128 + tid];
    __syncthreads();

    // A: sub-key scores + key build
    float a1, a2;
    {
        const float4* k1 = (const float4*)(sub_keys + tid * 64);
        const float4* k2 = (const float4*)(sub_keys + 8192 + tid * 64);
        float s1 = 0.f, s2 = 0.f;
#pragma unroll 4
        for (int c = 0; c < 16; c++) {
            float4 v1 = k1[c], v2 = k2[c];
            s1 = fmaf(qrow[4 * c + 0], v1.x, s1);
            s1 = fmaf(qrow[4 * c + 1], v1.y, s1);
            s1 = fmaf(qrow[4 * c + 2], v1.z, s1);
            s1 = fmaf(qrow[4 * c + 3], v1.w, s1);
            s2 = fmaf(qrow[64 + 4 * c + 0], v2.x, s2);
            s2 = fmaf(qrow[64 + 4 * c + 1], v2.y, s2);
            s2 = fmaf(qrow[64 + 4 * c + 2], v2.z, s2);
            s2 = fmaf(qrow[64 + 4 * c + 3], v2.w, s2);
        }
        a1 = s1; a2 = s2;
    }
    unsigned long long key1 = ((unsigned long long)obits(a1) << 32) | (unsigned)(127 - tid);
    unsigned long long key2 = ((unsigned long long)obits(a2) << 32) | (unsigned)(127 - tid);
    k1s[tid] = key1;
    k2s[tid] = key2;
    __syncthreads();

    // B: rank via u64 key compares (desc value, ties -> lower index)
    {
        int r1 = 0, r2 = 0;
#pragma unroll 4
        for (int j = 0; j < 128; j++) {
            r1 += (k1s[j] > key1);
            r2 += (k2s[j] > key2);
        }
        if (r1 < 16) { tv1[r1] = a1; ti1[r1] = tid; }
        if (r2 < 16) { tv2[r2] = a2; ti2[r2] = tid; }
    }
    __syncthreads();

    // C1: build all 256 candidate keys (sum value, ties -> lower expert id)
    {
        int c0 = tid, c1 = tid + 128;
        float s0 = tv1[c0 >> 4] + tv2[c0 & 15];
        int e0 = ti1[c0 >> 4] * 128 + ti2[c0 & 15];
        cks[c0] = ((unsigned long long)obits(s0) << 32) | (unsigned)(16383 - e0);
        float s1v = tv1[c1 >> 4] + tv2[c1 & 15];
        int e1 = ti1[c1 >> 4] * 128 + ti2[c1 & 15];
        cks[c1] = ((unsigned long long)obits(s1v) << 32) | (unsigned)(16383 - e1);
    }
    __syncthreads();

    // C2: rank staircase candidates {(i,j):(i+1)(j+1)<=16} vs all 256
    if (tid < 100) {
        int c = tid >> 1, h = tid & 1;
        int i, j;
        if      (c < 16) { i = 0; j = c; }
        else if (c < 24) { i = 1; j = c - 16; }
        else if (c < 29) { i = 2; j = c - 24; }
        else if (c < 33) { i = 3; j = c - 29; }
        else if (c < 36) { i = 4; j = c - 33; }
        else if (c < 38) { i = 5; j = c - 36; }
        else if (c < 40) { i = 6; j = c - 38; }
        else if (c < 42) { i = 7; j = c - 40; }
        else             { i = 8 + (c - 42); j = 0; }
        unsigned long long mk = cks[i * 16 + j];
        const unsigned long long* base = cks + h * 128;
        int cnt = 0;
#pragma unroll 4
        for (int t = 0; t < 128; t++) cnt += (base[t] > mk);
        part[tid] = cnt;
    }
    __syncthreads();
    if (tid < 50) {
        int r = part[2 * tid] + part[2 * tid + 1];
        if (r < 16) {
            int c = tid;
            int i, j;
            if      (c < 16) { i = 0; j = c; }
            else if (c < 24) { i = 1; j = c - 16; }
            else if (c < 29) { i = 2; j = c - 24; }
            else if (c < 33) { i = 3; j = c - 29; }
            else if (c < 36) { i = 4; j = c - 33; }
            else if (c < 38) { i = 5; j = c - 36; }
            else if (c < 40) { i = 6; j = c - 38; }
            else if (c < 42) { i = 7; j = c - 40; }
            else             { i = 8 + (c - 42); j = 0; }
            eid[r] = ti1[i] * 128 + ti2[j];
        }
    }
    __syncthreads();

    // D: sim via 8 threads per expert + shuffle reduce
    {
        int e = tid >> 3, g = tid & 7;
        const float4* e4 = (const float4*)(ew + (long)eid[e] * 128 + g * 16);
        const float* qb = qrow + g * 16;
        float acc = 0.f;
#pragma unroll 2
        for (int m = 0; m < 4; m++) {
            float4 v = e4[m];
            acc = fmaf(qb[4 * m + 0], v.x, acc);
            acc = fmaf(qb[4 * m + 1], v.y, acc);
            acc = fmaf(qb[4 * m + 2], v.z, acc);
            acc = fmaf(qb[4 * m + 3], v.w, acc);
        }
        acc += __shfl_down(acc, 4);
        acc += __shfl_down(acc, 2);
        acc += __shfl_down(acc, 1);
        if (g == 0) simv[e] = acc;
    }
    __syncthreads();

    if (tid < 16) {
        float mx = simv[0];
#pragma unroll
        for (int k = 1; k < 16; k++) mx = fmaxf(mx, simv[k]);
        rw[tid] = expf(simv[tid] - mx);
    }
    __syncthreads();

    {
        float wsum = 0.f;
#pragma unroll
        for (int k = 0; k < 16; k++) wsum += rw[k];
        float inv = 1.f / wsum;
        float o = 0.f;
#pragma unroll
        for (int k = 0; k < 16; k++)
            o = fmaf(rw[k], ew[(long)eid[k] * 128 + tid], o);
        out[(long)th * 128 + tid] = o * inv;
    }
}

// ---------------------------------------------------------------------------
// Fused attention softmax + head-mean.
// ---------------------------------------------------------------------------
__global__ __launch_bounds__(256) void softmax_mean(
    float* __restrict__ att, float* __restrict__ outw)
{
    int blk = blockIdx.x;          // b*512 + row
    int b = blk >> 9, row = blk & 511;
    int tid = threadIdx.x;
    int w = tid >> 6, lane = tid & 63;

    __shared__ float msum[4][516];

#pragma unroll
    for (int pass = 0; pass < 2; pass++) {
        int h = w + pass * 4;
        long base = ((long)(b * 8 + h) * 512 + row) * 512 + lane * 8;
        float4 v0 = *(const float4*)(att + base);
        float4 v1 = *(const float4*)(att + base + 4);
        float m = fmaxf(fmaxf(fmaxf(v0.x, v0.y), fmaxf(v0.z, v0.w)),
                        fmaxf(fmaxf(v1.x, v1.y), fmaxf(v1.z, v1.w)));
#pragma unroll
        for (int off = 32; off > 0; off >>= 1)
            m = fmaxf(m, __shfl_xor(m, off));
        float e[8];
        e[0] = expf(v0.x - m); e[1] = expf(v0.y - m);
        e[2] = expf(v0.z - m); e[3] = expf(v0.w - m);
        e[4] = expf(v1.x - m); e[5] = expf(v1.y - m);
        e[6] = expf(v1.z - m); e[7] = expf(v1.w - m);
        float s = e[0] + e[1] + e[2] + e[3] + e[4] + e[5] + e[6] + e[7];
#pragma unroll
        for (int off = 32; off > 0; off >>= 1)
            s += __shfl_xor(s, off);
        float inv = 1.f / s;
        float4 p0 = make_float4(e[0] * inv, e[1] * inv, e[2] * inv, e[3] * inv);
        float4 p1 = make_float4(e[4] * inv, e[5] * inv, e[6] * inv, e[7] * inv);
        *(float4*)(att + base) = p0;
        *(float4*)(att + base + 4) = p1;
        int c = lane * 8;
        if (pass == 0) {
            msum[w][c + 0] = p0.x; msum[w][c + 1] = p0.y;
            msum[w][c + 2] = p0.z; msum[w][c + 3] = p0.w;
            msum[w][c + 4] = p1.x; msum[w][c + 5] = p1.y;
            msum[w][c + 6] = p1.z; msum[w][c + 7] = p1.w;
        } else {
            msum[w][c + 0] += p0.x; msum[w][c + 1] += p0.y;
            msum[w][c + 2] += p0.z; msum[w][c + 3] += p0.w;
            msum[w][c + 4] += p1.x; msum[w][c + 5] += p1.y;
            msum[w][c + 6] += p1.z; msum[w][c + 7] += p1.w;
        }
    }
    __syncthreads();
#pragma unroll
    for (int i = 0; i < 2; i++) {
        int c = tid + i * 256;
        float s = (msum[0][c] + msum[1][c] + msum[2][c] + msum[3][c]) * 0.125f;
        outw[(long)blk * 512 + c] = s;
    }
}

// ---------------------------------------------------------------------------
__global__ __launch_bounds__(256) void final_fuse(
    const float* __restrict__ x, const float* __restrict__ out2,
    const float* __restrict__ ao2, const float* __restrict__ rms_w,
    float* __restrict__ y)
{
    long base = (long)blockIdx.x * 1024;
    int tid = threadIdx.x;
    float v[4];
    float ss = 0.f;
#pragma unroll
    for (int i = 0; i < 4; i++) {
        int d = tid + i * 256;
        v[i] = x[base + d] + out2[base + d] + ao2[base + d];
        ss = fmaf(v[i], v[i], ss);
    }
    __shared__ float red[256];
    red[tid] = ss;
    __syncthreads();
    for (int st = 128; st > 0; st >>= 1) {
        if (tid < st) red[tid] += red[tid + st];
        __syncthreads();
    }
    float scale = rsqrtf(red[0] * (1.f / 1024.f) + 1e-6f);
#pragma unroll
    for (int i = 0; i < 4; i++) {
        int d = tid + i * 256;
        y[base + d] = v[i] * scale * rms_w[d];
    }
}

// ---------------------------------------------------------------------------
extern "C" void kernel_launch(void* const* d_in, const int* in_sizes, int n_in,
                              void* d_out, int out_size, void* d_ws, size_t ws_size,
                              hipStream_t stream)
{
    const float* x         = (const float*)d_in[0];
    const float* wq        = (const float*)d_in[1];
    const float* bq        = (const float*)d_in[2];
    const float* bn_w      = (const float*)d_in[3];
    const float* bn_b      = (const float*)d_in[4];
    const float* bn_mean   = (const float*)d_in[5];
    const float* bn_var    = (const float*)d_in[6];
    const float* sub_keys  = (const float*)d_in[7];
    const float* ew        = (const float*)d_in[8];
    const float* wo        = (const float*)d_in[9];
    const float* bo        = (const float*)d_in[10];
    const float* in_proj_w = (const float*)d_in[11];
    const float* in_proj_b = (const float*)d_in[12];
    const float* attn_ow   = (const float*)d_in[13];
    const float* attn_ob   = (const float*)d_in[14];
    const float* rms_w     = (const float*)d_in[15];
    float* out = (float*)d_out;

    float* ws   = (float*)d_ws;
    float* q    = ws;                 // 1024x1024 (dead after peer; reused as vat)
    float* peer = ws + 1048576;       // 1024x1024
    float* out2 = ws + 2097152;       // 1024x1024
    float* qkv  = ws + 3145728;       // 1024x3072
    float* att  = ws + 6291456;       // 16x512x512
    float* ao   = ws + 10485760;      // 1024x1024
    float* ao2  = ws + 11534336;      // 1024x1024
    float* vat  = q;                  // 16x128x512 (aliases q)

    dim3 blk(256);

    // 1. q = BN(x @ wq^T + bq)   (fp32 exact, BN fused)
    sgemm_qproj<<<dim3(16, 16, 1), blk, 0, stream>>>(
        x, wq, q, bq, bn_w, bn_b, bn_mean, bn_var);

    // 2. PEER
    peer_kernel<<<8192, 128, 0, stream>>>(q, sub_keys, ew, peer);

    // 3. out2 = peer @ wo^T + bo   (256 blocks)
    gemm_mfma64<<<dim3(16, 16, 1), blk, 0, stream>>>(
        peer, 1024L, 0L, 0L, wo, 1024L, 0L, 0L, out2, 1024L, 0L, 0L,
        1024, bo, 1.0f, 1);

    // 4. qkv = x @ in_proj^T + b   (768 blocks)
    gemm_mfma64<<<dim3(48, 16, 1), blk, 0, stream>>>(
        x, 1024L, 0L, 0L, in_proj_w, 1024L, 0L, 0L, qkv, 3072L, 0L, 0L,
        1024, in_proj_b, 1.0f, 1);

    // 5. vat = va^T (q's slot is free now)
    transpose_va<<<dim3(16, 4, 16), blk, 0, stream>>>(qkv, vat);

    // 6. att scores = qa @ ka^T / sqrt(128)   (1024 blocks)
    gemm_mfma64<<<dim3(8, 8, 16), blk, 0, stream>>>(
        qkv, 3072L, 1572864L, 128L,
        qkv + 1024, 3072L, 1572864L, 128L,
        att, 512L, 2097152L, 262144L,
        128, nullptr, 0.08838834764831845f, 8);

    // 7. softmax + head-mean fused; mean -> out[1048576:]
    softmax_mean<<<1024, 256, 0, stream>>>(att, out + 1048576);

    // 8. ao = att @ vat^T   (256 blocks)
    gemm_mfma64<<<dim3(2, 8, 16), blk, 0, stream>>>(
        att, 512L, 2097152L, 262144L,
        vat, 512L, 524288L, 65536L,
        ao, 1024L, 524288L, 128L,
        512, nullptr, 1.0f, 8);

    // 9. ao2 = ao @ attn_ow^T + attn_ob   (256 blocks)
    gemm_mfma64<<<dim3(16, 16, 1), blk, 0, stream>>>(
        ao, 1024L, 0L, 0L, attn_ow, 1024L, 0L, 0L, ao2, 1024L, 0L, 0L,
        1024, attn_ob, 1.0f, 1);

    // 10. final fuse -> out[0:1048576]
    final_fuse<<<1024, 256, 0, stream>>>(x, out2, ao2, rms_w, out);
}

// Round 9
// 316.239 us; speedup vs baseline: 1.8521x; 1.0623x over previous
//
#include <hip/hip_runtime.h>
#include <hip/hip_bf16.h>
#include <math.h>

typedef __attribute__((ext_vector_type(8))) short bf16x8;
typedef __attribute__((ext_vector_type(4))) float f32x4;

__device__ inline short f2bf(float f) {
    __hip_bfloat16 h = __float2bfloat16(f);
    return *reinterpret_cast<short*>(&h);
}

// order-preserving float -> uint map (strictly monotone for non-NaN)
__device__ inline unsigned int obits(float f) {
    unsigned int u = __float_as_uint(f);
    return (u & 0x80000000u) ? ~u : (u | 0x80000000u);
}

// ---------------------------------------------------------------------------
// bf16 MFMA GEMM, 64x64 tile / 256 threads / 4 waves.
// Double-buffered LDS: ONE barrier per K-step; regs prefetched a tile ahead.
// C[m][n] = scale * sum_k A[m][k]*B[n][k] (+bias[n]).  K mult of 32.
// ---------------------------------------------------------------------------
__global__ __launch_bounds__(256) void gemm_mfma64(
    const float* __restrict__ A, long lda, long sAb, long sAh,
    const float* __restrict__ B, long ldb, long sBb, long sBh,
    float* __restrict__ C, long ldc, long sCb, long sCh,
    int K, const float* __restrict__ bias, float scale, int hDiv)
{
    int bz = blockIdx.z;
    int bb = bz / hDiv, hh = bz % hDiv;
    A += bb * sAb + hh * sAh;
    B += bb * sBb + hh * sBh;
    C += bb * sCb + hh * sCh;
    int bm = blockIdx.y * 64, bn = blockIdx.x * 64;

    __shared__ __align__(16) short Asub[2][2048];
    __shared__ __align__(16) short Bsub[2][2048];

    int tid = threadIdx.x;
    int lane = tid & 63;
    int wave = tid >> 6;
    int wr = wave >> 1, wc = wave & 1;
    int l15 = lane & 15, l4 = lane >> 4;

    f32x4 acc[2][2] = {};

    int sr = tid >> 2;   // row 0..63
    int sq = tid & 3;    // kgroup (8 floats)
    const float* gA = A + (long)(bm + sr) * lda + sq * 8;
    const float* gB = B + (long)(bn + sr) * ldb + sq * 8;
    int woff = (sr >> 4) * 512 + sq * 128 + (sr & 15) * 8;

    float4 a0 = *(const float4*)(gA);
    float4 a1 = *(const float4*)(gA + 4);
    float4 b0 = *(const float4*)(gB);
    float4 b1 = *(const float4*)(gB + 4);
    {   // stage tile 0 into buf 0
        bf16x8 ua, ub;
        ua[0]=f2bf(a0.x); ua[1]=f2bf(a0.y); ua[2]=f2bf(a0.z); ua[3]=f2bf(a0.w);
        ua[4]=f2bf(a1.x); ua[5]=f2bf(a1.y); ua[6]=f2bf(a1.z); ua[7]=f2bf(a1.w);
        ub[0]=f2bf(b0.x); ub[1]=f2bf(b0.y); ub[2]=f2bf(b0.z); ub[3]=f2bf(b0.w);
        ub[4]=f2bf(b1.x); ub[5]=f2bf(b1.y); ub[6]=f2bf(b1.z); ub[7]=f2bf(b1.w);
        *(bf16x8*)(Asub[0] + woff) = ua;
        *(bf16x8*)(Bsub[0] + woff) = ub;
    }
    if (K > 32) {   // prefetch tile 1 into regs
        a0 = *(const float4*)(gA + 32);
        a1 = *(const float4*)(gA + 36);
        b0 = *(const float4*)(gB + 32);
        b1 = *(const float4*)(gB + 36);
    }
    __syncthreads();

    int p = 0;
    for (int k0 = 0; k0 < K; k0 += 32) {
        bf16x8 af[2], bfr[2];
#pragma unroll
        for (int mi = 0; mi < 2; mi++)
            af[mi] = *(const bf16x8*)(Asub[p] + (wr * 2 + mi) * 512 + l4 * 128 + l15 * 8);
#pragma unroll
        for (int ni = 0; ni < 2; ni++)
            bfr[ni] = *(const bf16x8*)(Bsub[p] + (wc * 2 + ni) * 512 + l4 * 128 + l15 * 8);

        if (k0 + 32 < K) {   // stage next tile into other buffer
            bf16x8 ua, ub;
            ua[0]=f2bf(a0.x); ua[1]=f2bf(a0.y); ua[2]=f2bf(a0.z); ua[3]=f2bf(a0.w);
            ua[4]=f2bf(a1.x); ua[5]=f2bf(a1.y); ua[6]=f2bf(a1.z); ua[7]=f2bf(a1.w);
            ub[0]=f2bf(b0.x); ub[1]=f2bf(b0.y); ub[2]=f2bf(b0.z); ub[3]=f2bf(b0.w);
            ub[4]=f2bf(b1.x); ub[5]=f2bf(b1.y); ub[6]=f2bf(b1.z); ub[7]=f2bf(b1.w);
            *(bf16x8*)(Asub[p ^ 1] + woff) = ua;
            *(bf16x8*)(Bsub[p ^ 1] + woff) = ub;
            if (k0 + 64 < K) {   // prefetch tile after next
                a0 = *(const float4*)(gA + k0 + 64);
                a1 = *(const float4*)(gA + k0 + 68);
                b0 = *(const float4*)(gB + k0 + 64);
                b1 = *(const float4*)(gB + k0 + 68);
            }
        }

#pragma unroll
        for (int mi = 0; mi < 2; mi++)
#pragma unroll
            for (int ni = 0; ni < 2; ni++)
                acc[mi][ni] = __builtin_amdgcn_mfma_f32_16x16x32_bf16(
                    af[mi], bfr[ni], acc[mi][ni], 0, 0, 0);
        __syncthreads();
        p ^= 1;
    }

#pragma unroll
    for (int ni = 0; ni < 2; ni++) {
        int c = bn + wc * 32 + ni * 16 + l15;
        float bv = bias ? bias[c] : 0.f;
#pragma unroll
        for (int mi = 0; mi < 2; mi++) {
            int r0 = bm + wr * 32 + mi * 16 + l4 * 4;
#pragma unroll
            for (int e = 0; e < 4; e++)
                C[(long)(r0 + e) * ldc + c] = acc[mi][ni][e] * scale + bv;
        }
    }
}

// ---------------------------------------------------------------------------
// fp32 q-projection SGEMM with fused bias + BatchNorm epilogue.
// ---------------------------------------------------------------------------
__global__ __launch_bounds__(256) void sgemm_qproj(
    const float* __restrict__ A, const float* __restrict__ W,
    float* __restrict__ Q,
    const float* __restrict__ bq, const float* __restrict__ bn_w,
    const float* __restrict__ bn_b, const float* __restrict__ bn_mean,
    const float* __restrict__ bn_var)
{
    int bm = blockIdx.y * 64, bn = blockIdx.x * 64;
    __shared__ float As[32][64];
    __shared__ float Bs[32][64];
    int tid = threadIdx.x;
    int tx = tid & 15, ty = tid >> 4;
    int r = tid >> 2, q4 = tid & 3;
    float acc[4][4] = {{0.f}};

    const float* ga = A + (long)(bm + r) * 1024 + q4 * 8;
    const float* gb = W + (long)(bn + r) * 1024 + q4 * 8;

    float4 a0 = *(const float4*)(ga);
    float4 a1 = *(const float4*)(ga + 4);
    float4 b0 = *(const float4*)(gb);
    float4 b1 = *(const float4*)(gb + 4);

    for (int k0 = 0; k0 < 1024; k0 += 32) {
        __syncthreads();
        As[q4 * 8 + 0][r] = a0.x; As[q4 * 8 + 1][r] = a0.y;
        As[q4 * 8 + 2][r] = a0.z; As[q4 * 8 + 3][r] = a0.w;
        As[q4 * 8 + 4][r] = a1.x; As[q4 * 8 + 5][r] = a1.y;
        As[q4 * 8 + 6][r] = a1.z; As[q4 * 8 + 7][r] = a1.w;
        Bs[q4 * 8 + 0][r] = b0.x; Bs[q4 * 8 + 1][r] = b0.y;
        Bs[q4 * 8 + 2][r] = b0.z; Bs[q4 * 8 + 3][r] = b0.w;
        Bs[q4 * 8 + 4][r] = b1.x; Bs[q4 * 8 + 5][r] = b1.y;
        Bs[q4 * 8 + 6][r] = b1.z; Bs[q4 * 8 + 7][r] = b1.w;
        if (k0 + 32 < 1024) {
            a0 = *(const float4*)(ga + k0 + 32);
            a1 = *(const float4*)(ga + k0 + 36);
            b0 = *(const float4*)(gb + k0 + 32);
            b1 = *(const float4*)(gb + k0 + 36);
        }
        __syncthreads();
#pragma unroll
        for (int kk = 0; kk < 32; kk++) {
            float4 av = *(const float4*)&As[kk][ty * 4];
            float4 bv = *(const float4*)&Bs[kk][tx * 4];
            float a[4] = {av.x, av.y, av.z, av.w};
            float b[4] = {bv.x, bv.y, bv.z, bv.w};
#pragma unroll
            for (int i = 0; i < 4; i++)
#pragma unroll
                for (int j = 0; j < 4; j++)
                    acc[i][j] = fmaf(a[i], b[j], acc[i][j]);
        }
    }

#pragma unroll
    for (int j = 0; j < 4; j++) {
        int n = bn + tx * 4 + j;
        float s = rsqrtf(bn_var[n] + 1e-5f) * bn_w[n];
        float base = bq[n] - bn_mean[n];
        float bb = bn_b[n];
#pragma unroll
        for (int i = 0; i < 4; i++) {
            long m = bm + ty * 4 + i;
            Q[m * 1024 + n] = (acc[i][j] + base) * s + bb;
        }
    }
}

// ---------------------------------------------------------------------------
// va^T: vat[z][n][k] = va[b][k][h*128+n], z=b*8+h
// ---------------------------------------------------------------------------
__global__ __launch_bounds__(256) void transpose_va(
    const float* __restrict__ qkv, float* __restrict__ vat)
{
    int z = blockIdx.z;
    int b = z >> 3, h = z & 7;
    int k0 = blockIdx.x * 32, n0 = blockIdx.y * 32;
    __shared__ float tile[32][33];
    int tx = threadIdx.x & 31, ty = threadIdx.x >> 5;
    const float* src = qkv + 2048 + (long)b * 1572864 + (long)h * 128;
#pragma unroll
    for (int i = 0; i < 4; i++)
        tile[ty + 8 * i][tx] = src[(long)(k0 + ty + 8 * i) * 3072 + n0 + tx];
    __syncthreads();
    float* dst = vat + (long)z * 65536;
#pragma unroll
    for (int i = 0; i < 4; i++)
        dst[(long)(n0 + ty + 8 * i) * 512 + k0 + tx] = tile[tx][ty + 8 * i];
}

// ---------------------------------------------------------------------------
// Fused PEER v4: LDS-instruction-minimized.
// float4 rank reads (tie: val desc, idx asc), float4 qrow reads,
// b128 candidate-key reads. Selection identical to reference stable top-k.
// ---------------------------------------------------------------------------
__global__ __launch_bounds__(128) void peer_kernel(
    const float* __restrict__ q,        // (8192,128)
    const float* __restrict__ sub_keys, // (2,128,64)
    const float* __restrict__ ew,       // (16384,128)
    float* __restrict__ out)            // (8192,128)
{
    int th = blockIdx.x;
    int tid = threadIdx.x;

    __shared__ __align__(16) float qrow[128];
    __shared__ __align__(16) float s1s[128];
    __shared__ __align__(16) float s2s[128];
    __shared__ __align__(16) unsigned long long cks[256];
    __shared__ float tv1[16], tv2[16];
    __shared__ int   ti1[16], ti2[16];
    __shared__ int   part[100];
    __shared__ int   eid[16];
    __shared__ float simv[16];
    __shared__ float rw[16];

    qrow[tid] = q[(long)th * 128 + tid];
    __syncthreads();

    // A: sub-key scores (float4 qrow reads: 32 LDS instrs)
    float a1 = 0.f, a2 = 0.f;
    {
        const float4* k1 = (const float4*)(sub_keys + tid * 64);
        const float4* k2 = (const float4*)(sub_keys + 8192 + tid * 64);
#pragma unroll 4
        for (int c = 0; c < 16; c++) {
            float4 q1 = *(const float4*)&qrow[4 * c];
            float4 q2 = *(const float4*)&qrow[64 + 4 * c];
            float4 v1 = k1[c], v2 = k2[c];
            a1 = fmaf(q1.x, v1.x, a1); a1 = fmaf(q1.y, v1.y, a1);
            a1 = fmaf(q1.z, v1.z, a1); a1 = fmaf(q1.w, v1.w, a1);
            a2 = fmaf(q2.x, v2.x, a2); a2 = fmaf(q2.y, v2.y, a2);
            a2 = fmaf(q2.z, v2.z, a2); a2 = fmaf(q2.w, v2.w, a2);
        }
    }
    s1s[tid] = a1;
    s2s[tid] = a2;
    __syncthreads();

    // B: rank among 128 via float4 (desc value, ties -> lower index)
    {
        int r1 = 0, r2 = 0;
        for (int j = 0; j < 128; j += 4) {
            float4 a = *(const float4*)&s1s[j];
            float4 b = *(const float4*)&s2s[j];
            r1 += (a.x > a1) || (a.x == a1 && j + 0 < tid);
            r1 += (a.y > a1) || (a.y == a1 && j + 1 < tid);
            r1 += (a.z > a1) || (a.z == a1 && j + 2 < tid);
            r1 += (a.w > a1) || (a.w == a1 && j + 3 < tid);
            r2 += (b.x > a2) || (b.x == a2 && j + 0 < tid);
            r2 += (b.y > a2) || (b.y == a2 && j + 1 < tid);
            r2 += (b.z > a2) || (b.z == a2 && j + 2 < tid);
            r2 += (b.w > a2) || (b.w == a2 && j + 3 < tid);
        }
        if (r1 < 16) { tv1[r1] = a1; ti1[r1] = tid; }
        if (r2 < 16) { tv2[r2] = a2; ti2[r2] = tid; }
    }
    __syncthreads();

    // C1: 256 candidate u64 keys (sum value desc, ties -> lower expert id)
    {
        int c0 = tid, c1 = tid + 128;
        float s0 = tv1[c0 >> 4] + tv2[c0 & 15];
        int e0 = ti1[c0 >> 4] * 128 + ti2[c0 & 15];
        cks[c0] = ((unsigned long long)obits(s0) << 32) | (unsigned)(16383 - e0);
        float s1v = tv1[c1 >> 4] + tv2[c1 & 15];
        int e1 = ti1[c1 >> 4] * 128 + ti2[c1 & 15];
        cks[c1] = ((unsigned long long)obits(s1v) << 32) | (unsigned)(16383 - e1);
    }
    __syncthreads();

    // C2: rank staircase candidates {(i,j):(i+1)(j+1)<=16} vs all 256
    if (tid < 100) {
        int c = tid >> 1, h = tid & 1;
        int i, j;
        if      (c < 16) { i = 0; j = c; }
        else if (c < 24) { i = 1; j = c - 16; }
        else if (c < 29) { i = 2; j = c - 24; }
        else if (c < 33) { i = 3; j = c - 29; }
        else if (c < 36) { i = 4; j = c - 33; }
        else if (c < 38) { i = 5; j = c - 36; }
        else if (c < 40) { i = 6; j = c - 38; }
        else if (c < 42) { i = 7; j = c - 40; }
        else             { i = 8 + (c - 42); j = 0; }
        unsigned long long mk = cks[i * 16 + j];
        const ulonglong2* base = (const ulonglong2*)(cks + h * 128);
        int cnt = 0;
#pragma unroll 4
        for (int t = 0; t < 64; t++) {
            ulonglong2 kk = base[t];
            cnt += (kk.x > mk);
            cnt += (kk.y > mk);
        }
        part[tid] = cnt;
    }
    __syncthreads();
    if (tid < 50) {
        int r = part[2 * tid] + part[2 * tid + 1];
        if (r < 16) {
            int c = tid;
            int i, j;
            if      (c < 16) { i = 0; j = c; }
            else if (c < 24) { i = 1; j = c - 16; }
            else if (c < 29) { i = 2; j = c - 24; }
            else if (c < 33) { i = 3; j = c - 29; }
            else if (c < 36) { i = 4; j = c - 33; }
            else if (c < 38) { i = 5; j = c - 36; }
            else if (c < 40) { i = 6; j = c - 38; }
            else if (c < 42) { i = 7; j = c - 40; }
            else             { i = 8 + (c - 42); j = 0; }
            eid[r] = ti1[i] * 128 + ti2[j];
        }
    }
    __syncthreads();

    // D: sim via 8 threads per expert + shuffle reduce (float4 qrow reads)
    {
        int e = tid >> 3, g = tid & 7;
        const float4* e4 = (const float4*)(ew + (long)eid[e] * 128 + g * 16);
        const float4* qb = (const float4*)(qrow + g * 16);
        float acc = 0.f;
#pragma unroll
        for (int m = 0; m < 4; m++) {
            float4 v = e4[m];
            float4 qv = qb[m];
            acc = fmaf(qv.x, v.x, acc);
            acc = fmaf(qv.y, v.y, acc);
            acc = fmaf(qv.z, v.z, acc);
            acc = fmaf(qv.w, v.w, acc);
        }
        acc += __shfl_down(acc, 4);
        acc += __shfl_down(acc, 2);
        acc += __shfl_down(acc, 1);
        if (g == 0) simv[e] = acc;
    }
    __syncthreads();

    if (tid < 16) {
        float mx = simv[0];
#pragma unroll
        for (int k = 1; k < 16; k++) mx = fmaxf(mx, simv[k]);
        rw[tid] = expf(simv[tid] - mx);
    }
    __syncthreads();

    {
        float wsum = 0.f;
#pragma unroll
        for (int k = 0; k < 16; k++) wsum += rw[k];
        float inv = 1.f / wsum;
        float o = 0.f;
#pragma unroll
        for (int k = 0; k < 16; k++)
            o = fmaf(rw[k], ew[(long)eid[k] * 128 + tid], o);
        out[(long)th * 128 + tid] = o * inv;
    }
}

// ---------------------------------------------------------------------------
// Fused attention softmax + head-mean.
// ---------------------------------------------------------------------------
__global__ __launch_bounds__(256) void softmax_mean(
    float* __restrict__ att, float* __restrict__ outw)
{
    int blk = blockIdx.x;          // b*512 + row
    int b = blk >> 9, row = blk & 511;
    int tid = threadIdx.x;
    int w = tid >> 6, lane = tid & 63;

    __shared__ float msum[4][516];

#pragma unroll
    for (int pass = 0; pass < 2; pass++) {
        int h = w + pass * 4;
        long base = ((long)(b * 8 + h) * 512 + row) * 512 + lane * 8;
        float4 v0 = *(const float4*)(att + base);
        float4 v1 = *(const float4*)(att + base + 4);
        float m = fmaxf(fmaxf(fmaxf(v0.x, v0.y), fmaxf(v0.z, v0.w)),
                        fmaxf(fmaxf(v1.x, v1.y), fmaxf(v1.z, v1.w)));
#pragma unroll
        for (int off = 32; off > 0; off >>= 1)
            m = fmaxf(m, __shfl_xor(m, off));
        float e[8];
        e[0] = expf(v0.x - m); e[1] = expf(v0.y - m);
        e[2] = expf(v0.z - m); e[3] = expf(v0.w - m);
        e[4] = expf(v1.x - m); e[5] = expf(v1.y - m);
        e[6] = expf(v1.z - m); e[7] = expf(v1.w - m);
        float s = e[0] + e[1] + e[2] + e[3] + e[4] + e[5] + e[6] + e[7];
#pragma unroll
        for (int off = 32; off > 0; off >>= 1)
            s += __shfl_xor(s, off);
        float inv = 1.f / s;
        float4 p0 = make_float4(e[0] * inv, e[1] * inv, e[2] * inv, e[3] * inv);
        float4 p1 = make_float4(e[4] * inv, e[5] * inv, e[6] * inv, e[7] * inv);
        *(float4*)(att + base) = p0;
        *(float4*)(att + base + 4) = p1;
        int c = lane * 8;
        if (pass == 0) {
            msum[w][c + 0] = p0.x; msum[w][c + 1] = p0.y;
            msum[w][c + 2] = p0.z; msum[w][c + 3] = p0.w;
            msum[w][c + 4] = p1.x; msum[w][c + 5] = p1.y;
            msum[w][c + 6] = p1.z; msum[w][c + 7] = p1.w;
        } else {
            msum[w][c + 0] += p0.x; msum[w][c + 1] += p0.y;
            msum[w][c + 2] += p0.z; msum[w][c + 3] += p0.w;
            msum[w][c + 4] += p1.x; msum[w][c + 5] += p1.y;
            msum[w][c + 6] += p1.z; msum[w][c + 7] += p1.w;
        }
    }
    __syncthreads();
#pragma unroll
    for (int i = 0; i < 2; i++) {
        int c = tid + i * 256;
        float s = (msum[0][c] + msum[1][c] + msum[2][c] + msum[3][c]) * 0.125f;
        outw[(long)blk * 512 + c] = s;
    }
}

// ---------------------------------------------------------------------------
__global__ __launch_bounds__(256) void final_fuse(
    const float* __restrict__ x, const float* __restrict__ out2,
    const float* __restrict__ ao2, const float* __restrict__ rms_w,
    float* __restrict__ y)
{
    long base = (long)blockIdx.x * 1024;
    int tid = threadIdx.x;
    float v[4];
    float ss = 0.f;
#pragma unroll
    for (int i = 0; i < 4; i++) {
        int d = tid + i * 256;
        v[i] = x[base + d] + out2[base + d] + ao2[base + d];
        ss = fmaf(v[i], v[i], ss);
    }
    __shared__ float red[256];
    red[tid] = ss;
    __syncthreads();
    for (int st = 128; st > 0; st >>= 1) {
        if (tid < st) red[tid] += red[tid + st];
        __syncthreads();
    }
    float scale = rsqrtf(red[0] * (1.f / 1024.f) + 1e-6f);
#pragma unroll
    for (int i = 0; i < 4; i++) {
        int d = tid + i * 256;
        y[base + d] = v[i] * scale * rms_w[d];
    }
}

// ---------------------------------------------------------------------------
extern "C" void kernel_launch(void* const* d_in, const int* in_sizes, int n_in,
                              void* d_out, int out_size, void* d_ws, size_t ws_size,
                              hipStream_t stream)
{
    const float* x         = (const float*)d_in[0];
    const float* wq        = (const float*)d_in[1];
    const float* bq        = (const float*)d_in[2];
    const float* bn_w      = (const float*)d_in[3];
    const float* bn_b      = (const float*)d_in[4];
    const float* bn_mean   = (const float*)d_in[5];
    const float* bn_var    = (const float*)d_in[6];
    const float* sub_keys  = (const float*)d_in[7];
    const float* ew        = (const float*)d_in[8];
    const float* wo        = (const float*)d_in[9];
    const float* bo        = (const float*)d_in[10];
    const float* in_proj_w = (const float*)d_in[11];
    const float* in_proj_b = (const float*)d_in[12];
    const float* attn_ow   = (const float*)d_in[13];
    const float* attn_ob   = (const float*)d_in[14];
    const float* rms_w     = (const float*)d_in[15];
    float* out = (float*)d_out;

    float* ws   = (float*)d_ws;
    float* q    = ws;                 // 1024x1024 (dead after peer; reused as vat)
    float* peer = ws + 1048576;       // 1024x1024
    float* out2 = ws + 2097152;       // 1024x1024
    float* qkv  = ws + 3145728;       // 1024x3072
    float* att  = ws + 6291456;       // 16x512x512
    float* ao   = ws + 10485760;      // 1024x1024
    float* ao2  = ws + 11534336;      // 1024x1024
    float* vat  = q;                  // 16x128x512 (aliases q)

    dim3 blk(256);

    // 1. q = BN(x @ wq^T + bq)   (fp32 exact, BN fused)
    sgemm_qproj<<<dim3(16, 16, 1), blk, 0, stream>>>(
        x, wq, q, bq, bn_w, bn_b, bn_mean, bn_var);

    // 2. PEER
    peer_kernel<<<8192, 128, 0, stream>>>(q, sub_keys, ew, peer);

    // 3. out2 = peer @ wo^T + bo   (256 blocks)
    gemm_mfma64<<<dim3(16, 16, 1), blk, 0, stream>>>(
        peer, 1024L, 0L, 0L, wo, 1024L, 0L, 0L, out2, 1024L, 0L, 0L,
        1024, bo, 1.0f, 1);

    // 4. qkv = x @ in_proj^T + b   (768 blocks)
    gemm_mfma64<<<dim3(48, 16, 1), blk, 0, stream>>>(
        x, 1024L, 0L, 0L, in_proj_w, 1024L, 0L, 0L, qkv, 3072L, 0L, 0L,
        1024, in_proj_b, 1.0f, 1);

    // 5. vat = va^T (q's slot is free now)
    transpose_va<<<dim3(16, 4, 16), blk, 0, stream>>>(qkv, vat);

    // 6. att scores = qa @ ka^T / sqrt(128)   (1024 blocks)
    gemm_mfma64<<<dim3(8, 8, 16), blk, 0, stream>>>(
        qkv, 3072L, 1572864L, 128L,
        qkv + 1024, 3072L, 1572864L, 128L,
        att, 512L, 2097152L, 262144L,
        128, nullptr, 0.08838834764831845f, 8);

    // 7. softmax + head-mean fused; mean -> out[1048576:]
    softmax_mean<<<1024, 256, 0, stream>>>(att, out + 1048576);

    // 8. ao = att @ vat^T   (256 blocks)
    gemm_mfma64<<<dim3(2, 8, 16), blk, 0, stream>>>(
        att, 512L, 2097152L, 262144L,
        vat, 512L, 524288L, 65536L,
        ao, 1024L, 524288L, 128L,
        512, nullptr, 1.0f, 8);

    // 9. ao2 = ao @ attn_ow^T + attn_ob   (256 blocks)
    gemm_mfma64<<<dim3(16, 16, 1), blk, 0, stream>>>(
        ao, 1024L, 0L, 0L, attn_ow, 1024L, 0L, 0L, ao2, 1024L, 0L, 0L,
        1024, attn_ob, 1.0f, 1);

    // 10. final fuse -> out[0:1048576]
    final_fuse<<<1024, 256, 0, stream>>>(x, out2, ao2, rms_w, out);
}